// Round 2
// baseline (27936.160 us; speedup 1.0000x reference)
//
#include <hip/hip_runtime.h>
#include <stdint.h>

// Problem constants
#define Bsz 16
#define Tlen 800
#define EPROJS 512
#define DUNITS 1024
#define ATT 512
#define ODIM 5000
#define LMAX 96
#define OL 97
#define NTOK (OL*Bsz)
#define G4 (4*DUNITS)
#define KX 1536             // [z0(1024) ; att_c(512)]
#define KA1 2048            // [z0(1024) ; z1(1024)]
#define SOS_ID (ODIM-1)
#define NWG 512
#define TCH 25              // t per S2 chunk (32 chunks * 25 = 800)

typedef unsigned short u16;
typedef short bfrag8 __attribute__((ext_vector_type(8)));
typedef float f32x4 __attribute__((ext_vector_type(4)));

__device__ __forceinline__ float bf2f(u16 u){
  union { uint32_t u; float f; } v; v.u = ((uint32_t)u) << 16; return v.f;
}
__device__ __forceinline__ u16 f2bf(float f){
  union { float f; uint32_t u; } v; v.f = f;
  uint32_t r = v.u + 0x7FFFu + ((v.u >> 16) & 1u);
  return (u16)(r >> 16);
}
__device__ __forceinline__ float sigm(float x){ return 1.0f/(1.0f + __expf(-x)); }
__device__ __forceinline__ float tanh_f(float x){ return 1.0f - 2.0f/(__expf(2.0f*x) + 1.0f); }

__device__ __forceinline__ f32x4 mfma_loop(const u16* A, int lda,
                                           const u16* Bm, int ldb,
                                           int K, f32x4 acc){
  int lane = threadIdx.x & 63;
  const u16* pa = A + (size_t)(lane & 15) * lda + ((lane >> 4) * 8);
  const u16* pb = Bm + (size_t)(lane & 15) * ldb + ((lane >> 4) * 8);
  #pragma unroll 4
  for (int k = 0; k < K; k += 32){
    bfrag8 av = *(const bfrag8*)(pa + k);
    bfrag8 bv = *(const bfrag8*)(pb + k);
    acc = __builtin_amdgcn_mfma_f32_16x16x32_bf16(av, bv, acc, 0, 0, 0);
  }
  return acc;
}

// ---------------- setup kernels ----------------
__global__ __launch_bounds__(256) void k_zero(float* p, int n){
  int i = blockIdx.x*256 + threadIdx.x;
  if (i < n) p[i] = 0.f;
}
__global__ __launch_bounds__(256) void k_cvt(const float* src, u16* dst, int n){
  int i = blockIdx.x*256 + threadIdx.x, st = gridDim.x*256;
  for (; i < n; i += st) dst[i] = f2bf(src[i]);
}
// permuted-tile Wcat0: out[w][s][k]; row r=(s>>2)*1024+4w+(s&3); k<1024: Whh0, else Wih0 att cols
__global__ __launch_bounds__(256) void k_build_wc0p(const float* Whh0, const float* Wih0, u16* out){
  int i = blockIdx.x*256+threadIdx.x, n = 256*16*KX, st = gridDim.x*256;
  for (; i<n; i+=st){
    int k = i % KX, ws = i / KX;
    int s = ws & 15, w2 = ws >> 4;
    int r = (s>>2)*1024 + 4*w2 + (s&3);
    float v = (k < 1024) ? Whh0[(size_t)r*1024 + k] : Wih0[(size_t)r*KX + k];
    out[i] = f2bf(v);
  }
}
// permuted-tile Wcat1: k<1024: Wih1 (z0 half), else Whh1 (z1 half)
__global__ __launch_bounds__(256) void k_build_wc1p(const float* Wih1, const float* Whh1, u16* out){
  int i = blockIdx.x*256+threadIdx.x, n = 256*16*KA1, st = gridDim.x*256;
  for (; i<n; i+=st){
    int k = i % KA1, ws = i / KA1;
    int s = ws & 15, w2 = ws >> 4;
    int r = (s>>2)*1024 + 4*w2 + (s&3);
    float v = (k < 1024) ? Wih1[(size_t)r*1024 + k] : Whh1[(size_t)r*1024 + (k-1024)];
    out[i] = f2bf(v);
  }
}
__global__ __launch_bounds__(256) void k_build_wih0e(const float* Wih0, u16* out){
  int i = blockIdx.x*256+threadIdx.x, n = G4*DUNITS, st = gridDim.x*256;
  for (; i<n; i+=st){
    int j = i/DUNITS, k = i%DUNITS;
    out[i] = f2bf(Wih0[(size_t)j*KX + k]);
  }
}
__global__ __launch_bounds__(256) void k_build_aey(const float* embed, const int* ys_pad, u16* out){
  int i = blockIdx.x*256+threadIdx.x, n = NTOK*DUNITS, st = gridDim.x*256;
  for (; i<n; i+=st){
    int row = i / DUNITS, k = i % DUNITS;
    int l = row / Bsz, b = row % Bsz;
    int idx = (l == 0) ? SOS_ID : ys_pad[b*LMAX + (l-1)];
    out[i] = f2bf(embed[(size_t)idx*DUNITS + k]);
  }
}

__global__ __launch_bounds__(64) void k_gemm_preenc(const u16* hsb, const u16* Wenc,
                                                    const float* b_enc, u16* pre_enc){
  int bid = blockIdx.x;
  int m0 = (bid >> 5) * 16, n0 = (bid & 31) * 16;
  int lane = threadIdx.x & 63;
  int col = n0 + (lane & 15);
  float bias = b_enc[col];
  f32x4 acc = {bias, bias, bias, bias};
  acc = mfma_loop(hsb + (size_t)m0*EPROJS, EPROJS, Wenc + (size_t)n0*EPROJS, EPROJS, EPROJS, acc);
  int quad = lane >> 4;
  #pragma unroll
  for (int r = 0; r < 4; r++)
    pre_enc[(size_t)(m0 + quad*4 + r)*ATT + col] = f2bf(acc[r]);
}

__global__ __launch_bounds__(64) void k_gemm_pregate(const u16* Aey, const u16* Wih0e,
                                                     const float* b_ih0, const float* b_hh0, float* out){
  int bid = blockIdx.x;
  int m0 = (bid >> 8) * 16, n0 = (bid & 255) * 16;
  int lane = threadIdx.x & 63;
  int col = n0 + (lane & 15);
  float bias = b_ih0[col] + b_hh0[col];
  f32x4 acc = {bias, bias, bias, bias};
  acc = mfma_loop(Aey + (size_t)m0*DUNITS, DUNITS, Wih0e + (size_t)n0*DUNITS, DUNITS, DUNITS, acc);
  int quad = lane >> 4;
  #pragma unroll
  for (int r = 0; r < 4; r++)
    out[(size_t)(m0 + quad*4 + r)*G4 + col] = acc[r];
}

__global__ __launch_bounds__(64) void k_gemm_logits(const u16* zall, const u16* Woutb,
                                                    const float* b_out, float* logits){
  const int NT = 313;
  int bid = blockIdx.x;
  int m0 = (bid / NT) * 16, n0 = (bid % NT) * 16;
  int lane = threadIdx.x & 63;
  int col = n0 + (lane & 15);
  bool ok = col < ODIM;
  int brow = ok ? col : 0;
  float bias = ok ? b_out[col] : 0.f;
  f32x4 acc = {bias, bias, bias, bias};
  const u16* pa = zall + (size_t)m0*DUNITS + (size_t)(lane & 15)*DUNITS + (lane >> 4)*8;
  const u16* pb = Woutb + (size_t)brow*DUNITS + (lane >> 4)*8;
  #pragma unroll 4
  for (int k = 0; k < DUNITS; k += 32){
    bfrag8 av = *(const bfrag8*)(pa + k);
    bfrag8 bv = *(const bfrag8*)(pb + k);
    acc = __builtin_amdgcn_mfma_f32_16x16x32_bf16(av, bv, acc, 0, 0, 0);
  }
  int quad = lane >> 4;
  if (ok){
    #pragma unroll
    for (int r = 0; r < 4; r++)
      logits[(size_t)(m0 + quad*4 + r)*ODIM + col] = acc[r];
  }
}

__global__ __launch_bounds__(256) void k_nll(const float* logits, const int* ys_pad, float* nll){
  int n = blockIdx.x;
  int b = n & 15, l = n >> 4;
  const float* row = logits + (size_t)n * ODIM;
  __shared__ float red[256];
  float m = -1e30f;
  for (int i = threadIdx.x; i < ODIM; i += 256) m = fmaxf(m, row[i]);
  red[threadIdx.x] = m; __syncthreads();
  for (int s = 128; s > 0; s >>= 1){
    if (threadIdx.x < s) red[threadIdx.x] = fmaxf(red[threadIdx.x], red[threadIdx.x + s]);
    __syncthreads();
  }
  float M = red[0]; __syncthreads();
  float sum = 0.f;
  for (int i = threadIdx.x; i < ODIM; i += 256) sum += __expf(row[i] - M);
  red[threadIdx.x] = sum; __syncthreads();
  for (int s = 128; s > 0; s >>= 1){
    if (threadIdx.x < s) red[threadIdx.x] += red[threadIdx.x + s];
    __syncthreads();
  }
  if (threadIdx.x == 0){
    int tgt = (l < LMAX) ? ys_pad[b*LMAX + l] : (ODIM - 1);
    nll[n] = (M + __logf(red[0])) - row[tgt];
  }
}

__global__ __launch_bounds__(256) void k_loss(const float* nll, float* out){
  __shared__ float red[256];
  float s = 0.f;
  for (int i = threadIdx.x; i < NTOK; i += 256) s += nll[i];
  red[threadIdx.x] = s; __syncthreads();
  for (int st = 128; st > 0; st >>= 1){
    if (threadIdx.x < st) red[threadIdx.x] += red[threadIdx.x + st];
    __syncthreads();
  }
  if (threadIdx.x == 0) out[0] = red[0] * ((float)LMAX / (float)NTOK);
}

// ---------------- persistent recurrence kernel ----------------
// bar layout (ints, stride 32): grp[g]=g*32 (g<8), root=8*32, grpgen[g]=(9+g)*32, rootgen=17*32
__device__ __forceinline__ void grid_sync(int* bar, int epoch){
  __syncthreads();
  if (threadIdx.x == 0){
    __threadfence();
    int g = (int)(blockIdx.x >> 6);
    int* gc = bar + g*32;
    int* rc = bar + 8*32;
    int* gg = bar + (9+g)*32;
    int* rg = bar + 17*32;
    int prev = __hip_atomic_fetch_add(gc, 1, __ATOMIC_ACQ_REL, __HIP_MEMORY_SCOPE_AGENT);
    if (prev == 63){
      __hip_atomic_store(gc, 0, __ATOMIC_RELAXED, __HIP_MEMORY_SCOPE_AGENT);
      int rprev = __hip_atomic_fetch_add(rc, 1, __ATOMIC_ACQ_REL, __HIP_MEMORY_SCOPE_AGENT);
      if (rprev == 7){
        __hip_atomic_store(rc, 0, __ATOMIC_RELAXED, __HIP_MEMORY_SCOPE_AGENT);
        __hip_atomic_store(rg, epoch, __ATOMIC_RELEASE, __HIP_MEMORY_SCOPE_AGENT);
      } else {
        while (__hip_atomic_load(rg, __ATOMIC_ACQUIRE, __HIP_MEMORY_SCOPE_AGENT) < epoch)
          __builtin_amdgcn_s_sleep(2);
      }
      __hip_atomic_store(gg, epoch, __ATOMIC_RELEASE, __HIP_MEMORY_SCOPE_AGENT);
    } else {
      while (__hip_atomic_load(gg, __ATOMIC_ACQUIRE, __HIP_MEMORY_SCOPE_AGENT) < epoch)
        __builtin_amdgcn_s_sleep(2);
    }
    __threadfence();
  }
  __syncthreads();
}

__global__ __launch_bounds__(256, 2) void k_persist(
  const u16* __restrict__ peb, const u16* __restrict__ hsb,
  const u16* __restrict__ wc0p, const u16* __restrict__ wc1p, const u16* __restrict__ wdecb,
  const float* __restrict__ pg0, const float* __restrict__ b_ih1, const float* __restrict__ b_hh1,
  const float* __restrict__ gvec, const int* __restrict__ hlens,
  u16* xbuf, u16* a1b0, u16* a1b1, float* dpbuf,
  float* part_attc, float* part_S, u16* zall, int* bar)
{
  __shared__ __align__(16) u16 s_pe[TCH*512];    // 25600 B
  __shared__ __align__(16) u16 s_hs[TCH*512];    // 25600 B
  __shared__ __align__(16) float s_dp[512];      // 2048 B
  __shared__ __align__(16) float s_gv[512];      // 2048 B
  __shared__ __align__(16) float s_red[2048];    // 8192 B
  __shared__ float s_c[64];                      // 256 B
  __shared__ float s_bias[16];
  __shared__ float s_sp[4];

  int tid = threadIdx.x, blk = blockIdx.x;
  int wv = tid >> 6, ln = tid & 63;

  // S2 role: b = blk>>5, chunk = blk&31
  int s2_b = blk >> 5, s2_ch = blk & 31;
  int t0 = s2_ch * TCH;
  int hl = hlens[s2_b];

  // ---- init: stage LDS-persistent data ----
  {
    const bfrag8* src_pe = (const bfrag8*)(peb + ((size_t)(s2_b*Tlen + t0))*512);
    const bfrag8* src_hs = (const bfrag8*)(hsb + ((size_t)(s2_b*Tlen + t0))*512);
    for (int idx = tid; idx < TCH*512/8; idx += 256){
      ((bfrag8*)s_pe)[idx] = src_pe[idx];
      ((bfrag8*)s_hs)[idx] = src_hs[idx];
    }
    for (int a = tid; a < 512; a += 256) s_gv[a] = gvec[a];
    if (blk < 256 && tid < 16){
      int r = (tid>>2)*1024 + 4*blk + (tid&3);
      s_bias[tid] = b_ih1[r] + b_hh1[r];
    }
    if (tid < 64) s_c[tid] = 0.f;
  }
  __syncthreads();

  int epoch = 0;
  f32x4 acc0 = {0.f,0.f,0.f,0.f};   // held gates0 partial (WG>=256)

  for (int i = 0; i < OL; i++){
    const u16* a1r = (i & 1) ? a1b1 : a1b0;
    u16* a1w = (i & 1) ? a1b0 : a1b1;

    // ======== S1 ========
    if (blk < 256){
      if (i >= 1){
        // gates1 + cell1 for step i-1
        const u16* bt = wc1p + (size_t)blk*16*KA1;
        f32x4 acc = {0.f,0.f,0.f,0.f};
        acc = mfma_loop(a1r + wv*512, KA1, bt + wv*512, KA1, 512, acc);
        int q = ln >> 4;
        #pragma unroll
        for (int r = 0; r < 4; r++) s_red[wv*256 + (q*4+r)*16 + (ln & 15)] = acc[r];
        __syncthreads();
        {
          float val = s_red[tid] + s_red[256+tid] + s_red[512+tid] + s_red[768+tid]
                    + s_bias[tid & 15];
          s_red[1024 + tid] = val;
        }
        __syncthreads();
        if (tid < 64){
          int b = tid >> 2, jj = tid & 3;
          float gi = s_red[1024 + b*16 + jj];
          float gf = s_red[1024 + b*16 + 4 + jj];
          float gg = s_red[1024 + b*16 + 8 + jj];
          float go = s_red[1024 + b*16 + 12 + jj];
          float c = s_c[tid];
          float cn = sigm(gf)*c + sigm(gi)*tanh_f(gg);
          float h  = sigm(go)*tanh_f(cn);
          s_c[tid] = cn;
          u16 hb = f2bf(h);
          int d = 4*blk + jj;
          a1w[b*KA1 + 1024 + d] = hb;
          zall[((size_t)((i-1)*Bsz + b))*DUNITS + d] = hb;
        }
      }
    } else {
      int w = blk - 256;
      const u16* bt0 = wc0p + (size_t)w*16*KX;
      acc0 = (f32x4){0.f,0.f,0.f,0.f};
      acc0 = mfma_loop(xbuf + wv*256, KX, bt0 + wv*256, KX, 256, acc0);
      if (w < 32){
        const u16* btd = wdecb + (size_t)w*16*DUNITS;
        f32x4 ad = {0.f,0.f,0.f,0.f};
        ad = mfma_loop(xbuf + wv*256, KX, btd + wv*256, DUNITS, 256, ad);
        int q = ln >> 4;
        #pragma unroll
        for (int r = 0; r < 4; r++) s_red[wv*256 + (q*4+r)*16 + (ln & 15)] = ad[r];
        __syncthreads();
        {
          float val = s_red[tid] + s_red[256+tid] + s_red[512+tid] + s_red[768+tid];
          int b = tid >> 4, al = tid & 15;
          dpbuf[b*512 + w*16 + al] = val;
        }
      }
    }
    grid_sync(bar, ++epoch);

    // ======== S2: energies + online attc partials ========
    {
      for (int a = tid; a < 512; a += 256) s_dp[a] = dpbuf[s2_b*512 + a];
      __syncthreads();
      // hoist per-lane dp/gv slices to registers (kills LDS bank conflicts)
      float dpr[8], gvr[8];
      {
        float4 d1 = *(const float4*)&s_dp[ln*8];
        float4 d2 = *(const float4*)&s_dp[ln*8+4];
        float4 g1 = *(const float4*)&s_gv[ln*8];
        float4 g2 = *(const float4*)&s_gv[ln*8+4];
        dpr[0]=d1.x; dpr[1]=d1.y; dpr[2]=d1.z; dpr[3]=d1.w;
        dpr[4]=d2.x; dpr[5]=d2.y; dpr[6]=d2.z; dpr[7]=d2.w;
        gvr[0]=g1.x; gvr[1]=g1.y; gvr[2]=g1.z; gvr[3]=g1.w;
        gvr[4]=g2.x; gvr[5]=g2.y; gvr[6]=g2.z; gvr[7]=g2.w;
      }
      float attc[8];
      #pragma unroll
      for (int j = 0; j < 8; j++) attc[j] = 0.f;
      float sp = 0.f;
      for (int lt = wv; lt < TCH; lt += 4){
        int t = t0 + lt;
        bool valid = (t < hl);
        float e = 0.f;
        if (valid){
          bfrag8 pv = *(const bfrag8*)&s_pe[lt*512 + ln*8];
          #pragma unroll
          for (int j = 0; j < 8; j++){
            float x = bf2f(((u16*)&pv)[j]) + dpr[j];
            e += gvr[j] * tanh_f(x);
          }
        }
        #pragma unroll
        for (int off = 32; off > 0; off >>= 1) e += __shfl_xor(e, off, 64);
        float p = valid ? __expf(2.0f * e) : 0.f;
        if (ln == 0) sp += p;
        bfrag8 hv = *(const bfrag8*)&s_hs[lt*512 + ln*8];
        #pragma unroll
        for (int j = 0; j < 8; j++) attc[j] += p * bf2f(((u16*)&hv)[j]);
      }
      #pragma unroll
      for (int j = 0; j < 4; j++) ((float4*)&s_red[wv*512 + ln*8])[0].x = 0.f; // placate nothing
      // store wave partials (vectorized)
      *(float4*)&s_red[wv*512 + ln*8]     = make_float4(attc[0],attc[1],attc[2],attc[3]);
      *(float4*)&s_red[wv*512 + ln*8 + 4] = make_float4(attc[4],attc[5],attc[6],attc[7]);
      if (ln == 0) s_sp[wv] = sp;
      __syncthreads();
      for (int idx = tid; idx < 512; idx += 256){
        float v = s_red[idx] + s_red[512+idx] + s_red[1024+idx] + s_red[1536+idx];
        part_attc[((size_t)(s2_b*32 + s2_ch))*512 + idx] = v;
      }
      if (tid == 0) part_S[s2_b*32 + s2_ch] = s_sp[0]+s_sp[1]+s_sp[2]+s_sp[3];
    }
    grid_sync(bar, ++epoch);

    // ======== S3: attc reduce + normalize ========
    if (blk < 16){
      int b = blk;
      if (tid < 32) s_red[tid] = part_S[b*32 + tid];
      __syncthreads();
      if (tid == 0){
        float s = 0.f;
        for (int c2 = 0; c2 < 32; c2++) s += s_red[c2];
        s_red[32] = 1.0f / s;
      }
      __syncthreads();
      float rinv = s_red[32];
      for (int e = tid; e < 512; e += 256){
        float v = 0.f;
        for (int c2 = 0; c2 < 32; c2++) v += part_attc[((size_t)(b*32 + c2))*512 + e];
        xbuf[b*KX + 1024 + e] = f2bf(v * rinv);
      }
    }
    grid_sync(bar, ++epoch);

    // ======== S4: gates0 att-part + cell0 ========
    if (blk >= 256){
      int w = blk - 256;
      const u16* bt0 = wc0p + (size_t)w*16*KX;
      acc0 = mfma_loop(xbuf + 1024 + wv*128, KX, bt0 + 1024 + wv*128, KX, 128, acc0);
      int q = ln >> 4;
      #pragma unroll
      for (int r = 0; r < 4; r++) s_red[wv*256 + (q*4+r)*16 + (ln & 15)] = acc0[r];
      __syncthreads();
      {
        int b = tid >> 4, s = tid & 15;
        int r = (s>>2)*1024 + 4*w + (s&3);
        float val = s_red[tid] + s_red[256+tid] + s_red[512+tid] + s_red[768+tid]
                  + pg0[((size_t)(i*Bsz + b))*G4 + r];
        s_red[1024 + tid] = val;
      }
      __syncthreads();
      if (tid < 64){
        int b = tid >> 2, jj = tid & 3;
        float gi = s_red[1024 + b*16 + jj];
        float gf = s_red[1024 + b*16 + 4 + jj];
        float gg = s_red[1024 + b*16 + 8 + jj];
        float go = s_red[1024 + b*16 + 12 + jj];
        float c = s_c[tid];
        float cn = sigm(gf)*c + sigm(gi)*tanh_f(gg);
        float h  = sigm(go)*tanh_f(cn);
        s_c[tid] = cn;
        u16 hb = f2bf(h);
        int d = 4*w + jj;
        xbuf[b*KX + d] = hb;
        a1w[b*KA1 + d] = hb;
      }
    }
    grid_sync(bar, ++epoch);
  }

  // ======== tail: gates1 + cell1 for step 96 ========
  if (blk < 256){
    const u16* a1r = a1b1;   // iter 97 reads a1buf[97&1]
    const u16* bt = wc1p + (size_t)blk*16*KA1;
    f32x4 acc = {0.f,0.f,0.f,0.f};
    acc = mfma_loop(a1r + wv*512, KA1, bt + wv*512, KA1, 512, acc);
    int q = ln >> 4;
    #pragma unroll
    for (int r = 0; r < 4; r++) s_red[wv*256 + (q*4+r)*16 + (ln & 15)] = acc[r];
    __syncthreads();
    {
      float val = s_red[tid] + s_red[256+tid] + s_red[512+tid] + s_red[768+tid]
                + s_bias[tid & 15];
      s_red[1024 + tid] = val;
    }
    __syncthreads();
    if (tid < 64){
      int b = tid >> 2, jj = tid & 3;
      float gi = s_red[1024 + b*16 + jj];
      float gf = s_red[1024 + b*16 + 4 + jj];
      float gg = s_red[1024 + b*16 + 8 + jj];
      float go = s_red[1024 + b*16 + 12 + jj];
      float c = s_c[tid];
      float cn = sigm(gf)*c + sigm(gi)*tanh_f(gg);
      float h  = sigm(go)*tanh_f(cn);
      u16 hb = f2bf(h);
      int d = 4*blk + jj;
      zall[((size_t)(LMAX*Bsz + b))*DUNITS + d] = hb;
    }
  }
}

extern "C" void kernel_launch(void* const* d_in, const int* in_sizes, int n_in,
                              void* d_out, int out_size, void* d_ws, size_t ws_size,
                              hipStream_t stream)
{
  const float* hs     = (const float*)d_in[0];
  const int*   hlens  = (const int*)d_in[1];
  const int*   ys_pad = (const int*)d_in[2];
  const float* embed  = (const float*)d_in[3];
  const float* W_ih0  = (const float*)d_in[4];
  const float* W_hh0  = (const float*)d_in[5];
  const float* b_ih0  = (const float*)d_in[6];
  const float* b_hh0  = (const float*)d_in[7];
  const float* W_ih1  = (const float*)d_in[8];
  const float* W_hh1  = (const float*)d_in[9];
  const float* b_ih1  = (const float*)d_in[10];
  const float* b_hh1  = (const float*)d_in[11];
  const float* W_enc  = (const float*)d_in[12];
  const float* b_enc  = (const float*)d_in[13];
  const float* W_dec  = (const float*)d_in[14];
  const float* gvec   = (const float*)d_in[15];
  const float* W_out  = (const float*)d_in[16];
  const float* b_out  = (const float*)d_in[17];
  (void)in_sizes; (void)n_in; (void)out_size; (void)ws_size;

  char* w = (char*)d_ws;
  size_t off = 0;
  auto alloc = [&](size_t bytes)->char*{
    char* ptr = w + off;
    off += (bytes + 255) & ~(size_t)255;
    return ptr;
  };
  // --- zeroed state block ---
  int*   bar  = (int*)alloc(4096);
  u16*  xbuf  = (u16*)alloc(Bsz*KX*2);
  u16*  a1b0  = (u16*)alloc(Bsz*KA1*2);
  u16*  a1b1  = (u16*)alloc(Bsz*KA1*2);
  size_t state_bytes = off;
  // --- scratch ---
  float* dpbuf = (float*)alloc(Bsz*ATT*4);
  float* pattc = (float*)alloc((size_t)Bsz*32*512*4);
  float* pS    = (float*)alloc(Bsz*32*4);
  u16*  hsb    = (u16*)alloc((size_t)Bsz*Tlen*EPROJS*2);
  u16*  peb    = (u16*)alloc((size_t)Bsz*Tlen*ATT*2);
  u16*  wencb  = (u16*)alloc((size_t)ATT*EPROJS*2);
  u16*  wdecb  = (u16*)alloc((size_t)ATT*DUNITS*2);
  u16*  wc0p   = (u16*)alloc((size_t)G4*KX*2);
  u16*  wc1p   = (u16*)alloc((size_t)G4*KA1*2);
  u16*  woutb  = (u16*)alloc((size_t)ODIM*DUNITS*2);
  float* pg0   = (float*)alloc((size_t)NTOK*G4*4);
  u16*  zall   = (u16*)alloc((size_t)NTOK*DUNITS*2);
  float* logits= (float*)alloc((size_t)NTOK*ODIM*4);
  float* nll   = (float*)alloc(NTOK*4);
  // setup-only buffers aliased into logits region (dead once logits is written)
  u16*  wih0e  = (u16*)logits;
  u16*  aey    = (u16*)((char*)logits + (size_t)G4*DUNITS*2);

  {
    int n = (int)(state_bytes / 4);
    k_zero<<<(n + 255)/256, 256, 0, stream>>>((float*)w, n);
  }

  k_cvt<<<2048,256,0,stream>>>(hs, hsb, Bsz*Tlen*EPROJS);
  k_cvt<<<256,256,0,stream>>>(W_enc, wencb, ATT*EPROJS);
  k_cvt<<<512,256,0,stream>>>(W_dec, wdecb, ATT*DUNITS);
  k_cvt<<<2048,256,0,stream>>>(W_out, woutb, ODIM*DUNITS);
  k_build_wc0p<<<4096,256,0,stream>>>(W_hh0, W_ih0, wc0p);
  k_build_wc1p<<<4096,256,0,stream>>>(W_ih1, W_hh1, wc1p);
  k_build_wih0e<<<2048,256,0,stream>>>(W_ih0, wih0e);
  k_build_aey<<<1024,256,0,stream>>>(embed, ys_pad, aey);

  k_gemm_preenc<<<(Bsz*Tlen/16)*(ATT/16), 64, 0, stream>>>(hsb, wencb, b_enc, peb);
  k_gemm_pregate<<<OL*(G4/16), 64, 0, stream>>>(aey, wih0e, b_ih0, b_hh0, pg0);

  // persistent cooperative recurrence
  {
    void* args[] = {
      (void*)&peb, (void*)&hsb, (void*)&wc0p, (void*)&wc1p, (void*)&wdecb,
      (void*)&pg0, (void*)&b_ih1, (void*)&b_hh1, (void*)&gvec, (void*)&hlens,
      (void*)&xbuf, (void*)&a1b0, (void*)&a1b1, (void*)&dpbuf,
      (void*)&pattc, (void*)&pS, (void*)&zall, (void*)&bar
    };
    hipLaunchCooperativeKernel((const void*)k_persist, dim3(NWG), dim3(256),
                               args, 0, stream);
  }

  k_gemm_logits<<<OL*313, 64, 0, stream>>>(zall, woutb, b_out, logits);
  k_nll<<<NTOK,256,0,stream>>>(logits, ys_pad, nll);
  k_loss<<<1,256,0,stream>>>(nll, (float*)d_out);
}

// Round 4
// 6117.501 us; speedup vs baseline: 4.5666x; 4.5666x over previous
//
#include <hip/hip_runtime.h>
#include <stdint.h>

// Problem constants
#define Bsz 16
#define Tlen 800
#define EPROJS 512
#define DUNITS 1024
#define ATT 512
#define ODIM 5000
#define LMAX 96
#define OL 97
#define NTOK (OL*Bsz)
#define G4 (4*DUNITS)
#define KX 1536             // [z0(1024) ; att_c(512)]
#define KA1 2048            // [z0(1024) ; z1(1024)]
#define SOS_ID (ODIM-1)
#define NWG 512
#define TCH 25              // t per S2 chunk (32 chunks * 25 = 800)

typedef unsigned short u16;
typedef short bfrag8 __attribute__((ext_vector_type(8)));
typedef float f32x4 __attribute__((ext_vector_type(4)));

__device__ __forceinline__ float bf2f(u16 u){
  union { uint32_t u; float f; } v; v.u = ((uint32_t)u) << 16; return v.f;
}
__device__ __forceinline__ u16 f2bf(float f){
  union { float f; uint32_t u; } v; v.f = f;
  uint32_t r = v.u + 0x7FFFu + ((v.u >> 16) & 1u);
  return (u16)(r >> 16);
}
__device__ __forceinline__ float sigm(float x){ return 1.0f/(1.0f + __expf(-x)); }
__device__ __forceinline__ float tanh_f(float x){ return 1.0f - 2.0f/(__expf(2.0f*x) + 1.0f); }

__device__ __forceinline__ f32x4 mfma_loop(const u16* A, int lda,
                                           const u16* Bm, int ldb,
                                           int K, f32x4 acc){
  int lane = threadIdx.x & 63;
  const u16* pa = A + (size_t)(lane & 15) * lda + ((lane >> 4) * 8);
  const u16* pb = Bm + (size_t)(lane & 15) * ldb + ((lane >> 4) * 8);
  #pragma unroll 4
  for (int k = 0; k < K; k += 32){
    bfrag8 av = *(const bfrag8*)(pa + k);
    bfrag8 bv = *(const bfrag8*)(pb + k);
    acc = __builtin_amdgcn_mfma_f32_16x16x32_bf16(av, bv, acc, 0, 0, 0);
  }
  return acc;
}

// ---------------- setup kernels ----------------
__global__ __launch_bounds__(256) void k_zero(float* p, int n){
  int i = blockIdx.x*256 + threadIdx.x;
  if (i < n) p[i] = 0.f;
}
__global__ __launch_bounds__(256) void k_cvt(const float* src, u16* dst, int n){
  int i = blockIdx.x*256 + threadIdx.x, st = gridDim.x*256;
  for (; i < n; i += st) dst[i] = f2bf(src[i]);
}
// permuted-tile Wcat0: out[w][s][k]; row r=(s>>2)*1024+4w+(s&3); k<1024: Whh0, else Wih0 att cols
__global__ __launch_bounds__(256) void k_build_wc0p(const float* Whh0, const float* Wih0, u16* out){
  int i = blockIdx.x*256+threadIdx.x, n = 256*16*KX, st = gridDim.x*256;
  for (; i<n; i+=st){
    int k = i % KX, ws = i / KX;
    int s = ws & 15, w2 = ws >> 4;
    int r = (s>>2)*1024 + 4*w2 + (s&3);
    float v = (k < 1024) ? Whh0[(size_t)r*1024 + k] : Wih0[(size_t)r*KX + k];
    out[i] = f2bf(v);
  }
}
// permuted-tile Wcat1: k<1024: Wih1 (z0 half), else Whh1 (z1 half)
__global__ __launch_bounds__(256) void k_build_wc1p(const float* Wih1, const float* Whh1, u16* out){
  int i = blockIdx.x*256+threadIdx.x, n = 256*16*KA1, st = gridDim.x*256;
  for (; i<n; i+=st){
    int k = i % KA1, ws = i / KA1;
    int s = ws & 15, w2 = ws >> 4;
    int r = (s>>2)*1024 + 4*w2 + (s&3);
    float v = (k < 1024) ? Wih1[(size_t)r*1024 + k] : Whh1[(size_t)r*1024 + (k-1024)];
    out[i] = f2bf(v);
  }
}
__global__ __launch_bounds__(256) void k_build_wih0e(const float* Wih0, u16* out){
  int i = blockIdx.x*256+threadIdx.x, n = G4*DUNITS, st = gridDim.x*256;
  for (; i<n; i+=st){
    int j = i/DUNITS, k = i%DUNITS;
    out[i] = f2bf(Wih0[(size_t)j*KX + k]);
  }
}
__global__ __launch_bounds__(256) void k_build_aey(const float* embed, const int* ys_pad, u16* out){
  int i = blockIdx.x*256+threadIdx.x, n = NTOK*DUNITS, st = gridDim.x*256;
  for (; i<n; i+=st){
    int row = i / DUNITS, k = i % DUNITS;
    int l = row / Bsz, b = row % Bsz;
    int idx = (l == 0) ? SOS_ID : ys_pad[b*LMAX + (l-1)];
    out[i] = f2bf(embed[(size_t)idx*DUNITS + k]);
  }
}

__global__ __launch_bounds__(64) void k_gemm_preenc(const u16* hsb, const u16* Wenc,
                                                    const float* b_enc, u16* pre_enc){
  int bid = blockIdx.x;
  int m0 = (bid >> 5) * 16, n0 = (bid & 31) * 16;
  int lane = threadIdx.x & 63;
  int col = n0 + (lane & 15);
  float bias = b_enc[col];
  f32x4 acc = {bias, bias, bias, bias};
  acc = mfma_loop(hsb + (size_t)m0*EPROJS, EPROJS, Wenc + (size_t)n0*EPROJS, EPROJS, EPROJS, acc);
  int quad = lane >> 4;
  #pragma unroll
  for (int r = 0; r < 4; r++)
    pre_enc[(size_t)(m0 + quad*4 + r)*ATT + col] = f2bf(acc[r]);
}

__global__ __launch_bounds__(64) void k_gemm_pregate(const u16* Aey, const u16* Wih0e,
                                                     const float* b_ih0, const float* b_hh0, float* out){
  int bid = blockIdx.x;
  int m0 = (bid >> 8) * 16, n0 = (bid & 255) * 16;
  int lane = threadIdx.x & 63;
  int col = n0 + (lane & 15);
  float bias = b_ih0[col] + b_hh0[col];
  f32x4 acc = {bias, bias, bias, bias};
  acc = mfma_loop(Aey + (size_t)m0*DUNITS, DUNITS, Wih0e + (size_t)n0*DUNITS, DUNITS, DUNITS, acc);
  int quad = lane >> 4;
  #pragma unroll
  for (int r = 0; r < 4; r++)
    out[(size_t)(m0 + quad*4 + r)*G4 + col] = acc[r];
}

__global__ __launch_bounds__(64) void k_gemm_logits(const u16* zall, const u16* Woutb,
                                                    const float* b_out, float* logits){
  const int NT = 313;
  int bid = blockIdx.x;
  int m0 = (bid / NT) * 16, n0 = (bid % NT) * 16;
  int lane = threadIdx.x & 63;
  int col = n0 + (lane & 15);
  bool ok = col < ODIM;
  int brow = ok ? col : 0;
  float bias = ok ? b_out[col] : 0.f;
  f32x4 acc = {bias, bias, bias, bias};
  const u16* pa = zall + (size_t)m0*DUNITS + (size_t)(lane & 15)*DUNITS + (lane >> 4)*8;
  const u16* pb = Woutb + (size_t)brow*DUNITS + (lane >> 4)*8;
  #pragma unroll 4
  for (int k = 0; k < DUNITS; k += 32){
    bfrag8 av = *(const bfrag8*)(pa + k);
    bfrag8 bv = *(const bfrag8*)(pb + k);
    acc = __builtin_amdgcn_mfma_f32_16x16x32_bf16(av, bv, acc, 0, 0, 0);
  }
  int quad = lane >> 4;
  if (ok){
    #pragma unroll
    for (int r = 0; r < 4; r++)
      logits[(size_t)(m0 + quad*4 + r)*ODIM + col] = acc[r];
  }
}

__global__ __launch_bounds__(256) void k_nll(const float* logits, const int* ys_pad, float* nll){
  int n = blockIdx.x;
  int b = n & 15, l = n >> 4;
  const float* row = logits + (size_t)n * ODIM;
  __shared__ float red[256];
  float m = -1e30f;
  for (int i = threadIdx.x; i < ODIM; i += 256) m = fmaxf(m, row[i]);
  red[threadIdx.x] = m; __syncthreads();
  for (int s = 128; s > 0; s >>= 1){
    if (threadIdx.x < s) red[threadIdx.x] = fmaxf(red[threadIdx.x], red[threadIdx.x + s]);
    __syncthreads();
  }
  float M = red[0]; __syncthreads();
  float sum = 0.f;
  for (int i = threadIdx.x; i < ODIM; i += 256) sum += __expf(row[i] - M);
  red[threadIdx.x] = sum; __syncthreads();
  for (int s = 128; s > 0; s >>= 1){
    if (threadIdx.x < s) red[threadIdx.x] += red[threadIdx.x + s];
    __syncthreads();
  }
  if (threadIdx.x == 0){
    int tgt = (l < LMAX) ? ys_pad[b*LMAX + l] : (ODIM - 1);
    nll[n] = (M + __logf(red[0])) - row[tgt];
  }
}

__global__ __launch_bounds__(256) void k_loss(const float* nll, float* out){
  __shared__ float red[256];
  float s = 0.f;
  for (int i = threadIdx.x; i < NTOK; i += 256) s += nll[i];
  red[threadIdx.x] = s; __syncthreads();
  for (int st = 128; st > 0; st >>= 1){
    if (threadIdx.x < st) red[threadIdx.x] += red[threadIdx.x + st];
    __syncthreads();
  }
  if (threadIdx.x == 0) out[0] = red[0] * ((float)LMAX / (float)NTOK);
}

// ---------------- persistent recurrence kernel ----------------
// Barrier with RELAXED counters/spins and at most ONE release + ONE acquire
// fence per block per sync. Agent-scope ACQ/REL atomic ops on gfx950 emit L2
// writeback/invalidate per op (per-XCD L2 non-coherent); round 2 did that on
// EVERY spin iteration (~70us/sync). Standalone scoped fence spelling is
// __builtin_amdgcn_fence(order, "agent").
__device__ __forceinline__ void grid_sync(int* bar, int epoch, bool do_rel, bool do_acq){
  __syncthreads();
  if (threadIdx.x == 0){
    if (do_rel) __builtin_amdgcn_fence(__ATOMIC_RELEASE, "agent");
    int g = (int)(blockIdx.x >> 6);
    int* gc = bar + g*32;
    int* rc = bar + 8*32;
    int* gg = bar + (9+g)*32;
    int* rg = bar + 17*32;
    int prev = __hip_atomic_fetch_add(gc, 1, __ATOMIC_RELAXED, __HIP_MEMORY_SCOPE_AGENT);
    if (prev == 63){
      __hip_atomic_store(gc, 0, __ATOMIC_RELAXED, __HIP_MEMORY_SCOPE_AGENT);
      int rprev = __hip_atomic_fetch_add(rc, 1, __ATOMIC_RELAXED, __HIP_MEMORY_SCOPE_AGENT);
      if (rprev == 7){
        __hip_atomic_store(rc, 0, __ATOMIC_RELAXED, __HIP_MEMORY_SCOPE_AGENT);
        __hip_atomic_store(rg, epoch, __ATOMIC_RELAXED, __HIP_MEMORY_SCOPE_AGENT);
      } else {
        while (__hip_atomic_load(rg, __ATOMIC_RELAXED, __HIP_MEMORY_SCOPE_AGENT) < epoch)
          __builtin_amdgcn_s_sleep(2);
      }
      __hip_atomic_store(gg, epoch, __ATOMIC_RELAXED, __HIP_MEMORY_SCOPE_AGENT);
    } else {
      while (__hip_atomic_load(gg, __ATOMIC_RELAXED, __HIP_MEMORY_SCOPE_AGENT) < epoch)
        __builtin_amdgcn_s_sleep(2);
    }
    if (do_acq) __builtin_amdgcn_fence(__ATOMIC_ACQUIRE, "agent");
  }
  __syncthreads();
}

__global__ __launch_bounds__(256, 2) void k_persist(
  const u16* __restrict__ peb, const u16* __restrict__ hsb,
  const u16* __restrict__ wc0p, const u16* __restrict__ wc1p, const u16* __restrict__ wdecb,
  const float* __restrict__ pg0, const float* __restrict__ b_ih1, const float* __restrict__ b_hh1,
  const float* __restrict__ gvec, const int* __restrict__ hlens,
  u16* xbuf, u16* a1b0, u16* a1b1, float* dpbuf,
  float* part_attc, float* part_S, u16* zall, int* bar)
{
  __shared__ __align__(16) u16 s_pe[TCH*512];    // 25600 B
  __shared__ __align__(16) u16 s_hs[TCH*512];    // 25600 B
  __shared__ __align__(16) float s_dp[512];      // 2048 B
  __shared__ __align__(16) float s_gv[512];      // 2048 B
  __shared__ __align__(16) float s_red[2048];    // 8192 B
  __shared__ float s_c[64];                      // 256 B
  __shared__ float s_bias[16];
  __shared__ float s_sp[4];

  int tid = threadIdx.x, blk = blockIdx.x;
  int wv = tid >> 6, ln = tid & 63;

  // S2 role: b = blk>>5, chunk = blk&31
  int s2_b = blk >> 5, s2_ch = blk & 31;
  int t0 = s2_ch * TCH;
  int hl = hlens[s2_b];

  // ---- init: stage LDS-persistent data ----
  {
    const bfrag8* src_pe = (const bfrag8*)(peb + ((size_t)(s2_b*Tlen + t0))*512);
    const bfrag8* src_hs = (const bfrag8*)(hsb + ((size_t)(s2_b*Tlen + t0))*512);
    for (int idx = tid; idx < TCH*512/8; idx += 256){
      ((bfrag8*)s_pe)[idx] = src_pe[idx];
      ((bfrag8*)s_hs)[idx] = src_hs[idx];
    }
    for (int a = tid; a < 512; a += 256) s_gv[a] = gvec[a];
    if (blk < 256 && tid < 16){
      int r = (tid>>2)*1024 + 4*blk + (tid&3);
      s_bias[tid] = b_ih1[r] + b_hh1[r];
    }
    if (tid < 64) s_c[tid] = 0.f;
  }
  __syncthreads();

  int epoch = 0;
  f32x4 acc0 = {0.f,0.f,0.f,0.f};   // held gates0 partial (WG>=256)

  for (int i = 0; i < OL; i++){
    const u16* a1r = (i & 1) ? a1b1 : a1b0;
    u16* a1w = (i & 1) ? a1b0 : a1b1;

    // ======== S1 ========
    if (blk < 256){
      if (i >= 1){
        // gates1 + cell1 for step i-1
        const u16* bt = wc1p + (size_t)blk*16*KA1;
        f32x4 acc = {0.f,0.f,0.f,0.f};
        acc = mfma_loop(a1r + wv*512, KA1, bt + wv*512, KA1, 512, acc);
        int q = ln >> 4;
        #pragma unroll
        for (int r = 0; r < 4; r++) s_red[wv*256 + (q*4+r)*16 + (ln & 15)] = acc[r];
        __syncthreads();
        {
          float val = s_red[tid] + s_red[256+tid] + s_red[512+tid] + s_red[768+tid]
                    + s_bias[tid & 15];
          s_red[1024 + tid] = val;
        }
        __syncthreads();
        if (tid < 64){
          int b = tid >> 2, jj = tid & 3;
          float gi = s_red[1024 + b*16 + jj];
          float gf = s_red[1024 + b*16 + 4 + jj];
          float gg = s_red[1024 + b*16 + 8 + jj];
          float go = s_red[1024 + b*16 + 12 + jj];
          float c = s_c[tid];
          float cn = sigm(gf)*c + sigm(gi)*tanh_f(gg);
          float h  = sigm(go)*tanh_f(cn);
          s_c[tid] = cn;
          u16 hb = f2bf(h);
          int d = 4*blk + jj;
          a1w[b*KA1 + 1024 + d] = hb;
          zall[((size_t)((i-1)*Bsz + b))*DUNITS + d] = hb;
        }
      }
    } else {
      int w = blk - 256;
      const u16* bt0 = wc0p + (size_t)w*16*KX;
      acc0 = (f32x4){0.f,0.f,0.f,0.f};
      acc0 = mfma_loop(xbuf + wv*256, KX, bt0 + wv*256, KX, 256, acc0);
      if (w < 32){
        const u16* btd = wdecb + (size_t)w*16*DUNITS;
        f32x4 ad = {0.f,0.f,0.f,0.f};
        ad = mfma_loop(xbuf + wv*256, KX, btd + wv*256, DUNITS, 256, ad);
        int q = ln >> 4;
        #pragma unroll
        for (int r = 0; r < 4; r++) s_red[wv*256 + (q*4+r)*16 + (ln & 15)] = ad[r];
        __syncthreads();
        {
          float val = s_red[tid] + s_red[256+tid] + s_red[512+tid] + s_red[768+tid];
          int b = tid >> 4, al = tid & 15;
          dpbuf[b*512 + w*16 + al] = val;
        }
      }
    }
    // rel: role-A wrote a1/zall (only when i>=1); blocks 256..287 wrote dpbuf.
    // acq: everyone reads dpbuf in S2.
    {
      bool rel = (blk < 256) ? (i >= 1) : (blk < 288);
      grid_sync(bar, ++epoch, rel, true);
    }

    // ======== S2: energies + online attc partials ========
    {
      for (int a = tid; a < 512; a += 256) s_dp[a] = dpbuf[s2_b*512 + a];
      __syncthreads();
      // hoist per-lane dp/gv slices to registers
      float dpr[8], gvr[8];
      {
        float4 d1 = *(const float4*)&s_dp[ln*8];
        float4 d2 = *(const float4*)&s_dp[ln*8+4];
        float4 g1 = *(const float4*)&s_gv[ln*8];
        float4 g2 = *(const float4*)&s_gv[ln*8+4];
        dpr[0]=d1.x; dpr[1]=d1.y; dpr[2]=d1.z; dpr[3]=d1.w;
        dpr[4]=d2.x; dpr[5]=d2.y; dpr[6]=d2.z; dpr[7]=d2.w;
        gvr[0]=g1.x; gvr[1]=g1.y; gvr[2]=g1.z; gvr[3]=g1.w;
        gvr[4]=g2.x; gvr[5]=g2.y; gvr[6]=g2.z; gvr[7]=g2.w;
      }
      float attc[8];
      #pragma unroll
      for (int j = 0; j < 8; j++) attc[j] = 0.f;
      float sp = 0.f;
      for (int lt = wv; lt < TCH; lt += 4){
        int t = t0 + lt;
        bool valid = (t < hl);
        float e = 0.f;
        if (valid){
          bfrag8 pv = *(const bfrag8*)&s_pe[lt*512 + ln*8];
          #pragma unroll
          for (int j = 0; j < 8; j++){
            float x = bf2f(((u16*)&pv)[j]) + dpr[j];
            e += gvr[j] * tanh_f(x);
          }
        }
        #pragma unroll
        for (int off = 32; off > 0; off >>= 1) e += __shfl_xor(e, off, 64);
        float p = valid ? __expf(2.0f * e) : 0.f;
        if (ln == 0) sp += p;
        bfrag8 hv = *(const bfrag8*)&s_hs[lt*512 + ln*8];
        #pragma unroll
        for (int j = 0; j < 8; j++) attc[j] += p * bf2f(((u16*)&hv)[j]);
      }
      *(float4*)&s_red[wv*512 + ln*8]     = make_float4(attc[0],attc[1],attc[2],attc[3]);
      *(float4*)&s_red[wv*512 + ln*8 + 4] = make_float4(attc[4],attc[5],attc[6],attc[7]);
      if (ln == 0) s_sp[wv] = sp;
      __syncthreads();
      for (int idx = tid; idx < 512; idx += 256){
        float v = s_red[idx] + s_red[512+idx] + s_red[1024+idx] + s_red[1536+idx];
        part_attc[((size_t)(s2_b*32 + s2_ch))*512 + idx] = v;
      }
      if (tid == 0) part_S[s2_b*32 + s2_ch] = s_sp[0]+s_sp[1]+s_sp[2]+s_sp[3];
    }
    // rel: all wrote partials. acq: only the 16 S3 blocks read them.
    grid_sync(bar, ++epoch, true, blk < 16);

    // ======== S3: attc reduce + normalize ========
    if (blk < 16){
      int b = blk;
      if (tid < 32) s_red[tid] = part_S[b*32 + tid];
      __syncthreads();
      if (tid == 0){
        float s = 0.f;
        for (int c2 = 0; c2 < 32; c2++) s += s_red[c2];
        s_red[32] = 1.0f / s;
      }
      __syncthreads();
      float rinv = s_red[32];
      for (int e = tid; e < 512; e += 256){
        float v = 0.f;
        for (int c2 = 0; c2 < 32; c2++) v += part_attc[((size_t)(b*32 + c2))*512 + e];
        xbuf[b*KX + 1024 + e] = f2bf(v * rinv);
      }
    }
    // rel: 16 blocks wrote xbuf att part. acq: role-B reads it in S4.
    grid_sync(bar, ++epoch, blk < 16, blk >= 256);

    // ======== S4: gates0 att-part + cell0 ========
    if (blk >= 256){
      int w = blk - 256;
      const u16* bt0 = wc0p + (size_t)w*16*KX;
      acc0 = mfma_loop(xbuf + 1024 + wv*128, KX, bt0 + 1024 + wv*128, KX, 128, acc0);
      int q = ln >> 4;
      #pragma unroll
      for (int r = 0; r < 4; r++) s_red[wv*256 + (q*4+r)*16 + (ln & 15)] = acc0[r];
      __syncthreads();
      {
        int b = tid >> 4, s = tid & 15;
        int r = (s>>2)*1024 + 4*w + (s&3);
        float val = s_red[tid] + s_red[256+tid] + s_red[512+tid] + s_red[768+tid]
                  + pg0[((size_t)(i*Bsz + b))*G4 + r];
        s_red[1024 + tid] = val;
      }
      __syncthreads();
      if (tid < 64){
        int b = tid >> 2, jj = tid & 3;
        float gi = s_red[1024 + b*16 + jj];
        float gf = s_red[1024 + b*16 + 4 + jj];
        float gg = s_red[1024 + b*16 + 8 + jj];
        float go = s_red[1024 + b*16 + 12 + jj];
        float c = s_c[tid];
        float cn = sigm(gf)*c + sigm(gi)*tanh_f(gg);
        float h  = sigm(go)*tanh_f(cn);
        s_c[tid] = cn;
        u16 hb = f2bf(h);
        int d = 4*w + jj;
        xbuf[b*KX + d] = hb;
        a1w[b*KA1 + d] = hb;
      }
    }
    // rel: role-B wrote xbuf z0 / a1w z0. acq: everyone (role-A reads a1 in
    // next S1; 256..287 read xbuf for dp; role-B reads xbuf z0 slice).
    grid_sync(bar, ++epoch, blk >= 256, true);
  }

  // ======== tail: gates1 + cell1 for step 96 ========
  if (blk < 256){
    const u16* a1r = a1b1;   // iter 97 reads a1buf[97&1]
    const u16* bt = wc1p + (size_t)blk*16*KA1;
    f32x4 acc = {0.f,0.f,0.f,0.f};
    acc = mfma_loop(a1r + wv*512, KA1, bt + wv*512, KA1, 512, acc);
    int q = ln >> 4;
    #pragma unroll
    for (int r = 0; r < 4; r++) s_red[wv*256 + (q*4+r)*16 + (ln & 15)] = acc[r];
    __syncthreads();
    {
      float val = s_red[tid] + s_red[256+tid] + s_red[512+tid] + s_red[768+tid]
                + s_bias[tid & 15];
      s_red[1024 + tid] = val;
    }
    __syncthreads();
    if (tid < 64){
      int b = tid >> 2, jj = tid & 3;
      float gi = s_red[1024 + b*16 + jj];
      float gf = s_red[1024 + b*16 + 4 + jj];
      float gg = s_red[1024 + b*16 + 8 + jj];
      float go = s_red[1024 + b*16 + 12 + jj];
      float c = s_c[tid];
      float cn = sigm(gf)*c + sigm(gi)*tanh_f(gg);
      float h  = sigm(go)*tanh_f(cn);
      u16 hb = f2bf(h);
      int d = 4*blk + jj;
      zall[((size_t)(LMAX*Bsz + b))*DUNITS + d] = hb;
    }
  }
}

extern "C" void kernel_launch(void* const* d_in, const int* in_sizes, int n_in,
                              void* d_out, int out_size, void* d_ws, size_t ws_size,
                              hipStream_t stream)
{
  const float* hs     = (const float*)d_in[0];
  const int*   hlens  = (const int*)d_in[1];
  const int*   ys_pad = (const int*)d_in[2];
  const float* embed  = (const float*)d_in[3];
  const float* W_ih0  = (const float*)d_in[4];
  const float* W_hh0  = (const float*)d_in[5];
  const float* b_ih0  = (const float*)d_in[6];
  const float* b_hh0  = (const float*)d_in[7];
  const float* W_ih1  = (const float*)d_in[8];
  const float* W_hh1  = (const float*)d_in[9];
  const float* b_ih1  = (const float*)d_in[10];
  const float* b_hh1  = (const float*)d_in[11];
  const float* W_enc  = (const float*)d_in[12];
  const float* b_enc  = (const float*)d_in[13];
  const float* W_dec  = (const float*)d_in[14];
  const float* gvec   = (const float*)d_in[15];
  const float* W_out  = (const float*)d_in[16];
  const float* b_out  = (const float*)d_in[17];
  (void)in_sizes; (void)n_in; (void)out_size; (void)ws_size;

  char* w = (char*)d_ws;
  size_t off = 0;
  auto alloc = [&](size_t bytes)->char*{
    char* ptr = w + off;
    off += (bytes + 255) & ~(size_t)255;
    return ptr;
  };
  // --- zeroed state block ---
  int*   bar  = (int*)alloc(4096);
  u16*  xbuf  = (u16*)alloc(Bsz*KX*2);
  u16*  a1b0  = (u16*)alloc(Bsz*KA1*2);
  u16*  a1b1  = (u16*)alloc(Bsz*KA1*2);
  size_t state_bytes = off;
  // --- scratch ---
  float* dpbuf = (float*)alloc(Bsz*ATT*4);
  float* pattc = (float*)alloc((size_t)Bsz*32*512*4);
  float* pS    = (float*)alloc(Bsz*32*4);
  u16*  hsb    = (u16*)alloc((size_t)Bsz*Tlen*EPROJS*2);
  u16*  peb    = (u16*)alloc((size_t)Bsz*Tlen*ATT*2);
  u16*  wencb  = (u16*)alloc((size_t)ATT*EPROJS*2);
  u16*  wdecb  = (u16*)alloc((size_t)ATT*DUNITS*2);
  u16*  wc0p   = (u16*)alloc((size_t)G4*KX*2);
  u16*  wc1p   = (u16*)alloc((size_t)G4*KA1*2);
  u16*  woutb  = (u16*)alloc((size_t)ODIM*DUNITS*2);
  float* pg0   = (float*)alloc((size_t)NTOK*G4*4);
  u16*  zall   = (u16*)alloc((size_t)NTOK*DUNITS*2);
  float* logits= (float*)alloc((size_t)NTOK*ODIM*4);
  float* nll   = (float*)alloc(NTOK*4);
  // setup-only buffers aliased into logits region (dead once logits is written)
  u16*  wih0e  = (u16*)logits;
  u16*  aey    = (u16*)((char*)logits + (size_t)G4*DUNITS*2);

  {
    int n = (int)(state_bytes / 4);
    k_zero<<<(n + 255)/256, 256, 0, stream>>>((float*)w, n);
  }

  k_cvt<<<2048,256,0,stream>>>(hs, hsb, Bsz*Tlen*EPROJS);
  k_cvt<<<256,256,0,stream>>>(W_enc, wencb, ATT*EPROJS);
  k_cvt<<<512,256,0,stream>>>(W_dec, wdecb, ATT*DUNITS);
  k_cvt<<<2048,256,0,stream>>>(W_out, woutb, ODIM*DUNITS);
  k_build_wc0p<<<4096,256,0,stream>>>(W_hh0, W_ih0, wc0p);
  k_build_wc1p<<<4096,256,0,stream>>>(W_ih1, W_hh1, wc1p);
  k_build_wih0e<<<2048,256,0,stream>>>(W_ih0, wih0e);
  k_build_aey<<<1024,256,0,stream>>>(embed, ys_pad, aey);

  k_gemm_preenc<<<(Bsz*Tlen/16)*(ATT/16), 64, 0, stream>>>(hsb, wencb, b_enc, peb);
  k_gemm_pregate<<<OL*(G4/16), 64, 0, stream>>>(aey, wih0e, b_ih0, b_hh0, pg0);

  // persistent cooperative recurrence
  {
    void* args[] = {
      (void*)&peb, (void*)&hsb, (void*)&wc0p, (void*)&wc1p, (void*)&wdecb,
      (void*)&pg0, (void*)&b_ih1, (void*)&b_hh1, (void*)&gvec, (void*)&hlens,
      (void*)&xbuf, (void*)&a1b0, (void*)&a1b1, (void*)&dpbuf,
      (void*)&pattc, (void*)&pS, (void*)&zall, (void*)&bar
    };
    hipLaunchCooperativeKernel((const void*)k_persist, dim3(NWG), dim3(256),
                               args, 0, stream);
  }

  k_gemm_logits<<<OL*313, 64, 0, stream>>>(zall, woutb, b_out, logits);
  k_nll<<<NTOK,256,0,stream>>>(logits, ys_pad, nll);
  k_loss<<<1,256,0,stream>>>(nll, (float*)d_out);
}

// Round 5
// 5388.391 us; speedup vs baseline: 5.1845x; 1.1353x over previous
//
#include <hip/hip_runtime.h>
#include <stdint.h>

// Problem constants
#define Bsz 16
#define Tlen 800
#define EPROJS 512
#define DUNITS 1024
#define ATT 512
#define ODIM 5000
#define LMAX 96
#define OL 97
#define NTOK (OL*Bsz)
#define G4 (4*DUNITS)
#define KX 1536             // [z0(1024) ; att_c(512)]
#define KA1 2048            // [z0(1024) ; z1(1024)]
#define SOS_ID (ODIM-1)
#define NWG 512
#define TCH 25              // t per S2 chunk (32 chunks * 25 = 800)

typedef unsigned short u16;
typedef unsigned int u32;
typedef unsigned long long u64;
typedef short bfrag8 __attribute__((ext_vector_type(8)));
typedef float f32x4 __attribute__((ext_vector_type(4)));

__device__ __forceinline__ float bf2f(u16 u){
  union { uint32_t u; float f; } v; v.u = ((uint32_t)u) << 16; return v.f;
}
__device__ __forceinline__ u16 f2bf(float f){
  union { float f; uint32_t u; } v; v.f = f;
  uint32_t r = v.u + 0x7FFFu + ((v.u >> 16) & 1u);
  return (u16)(r >> 16);
}
__device__ __forceinline__ float sigm(float x){ return 1.0f/(1.0f + __expf(-x)); }
__device__ __forceinline__ float tanh_f(float x){ return 1.0f - 2.0f/(__expf(2.0f*x) + 1.0f); }

// ---- LLC-coherent (agent-scope relaxed atomic) access: bypasses L1/L2, no
// cache-maintenance instructions. All cross-block communication uses these.
__device__ __forceinline__ u64 ald64(const void* p){
  return __hip_atomic_load((const u64*)p, __ATOMIC_RELAXED, __HIP_MEMORY_SCOPE_AGENT);
}
__device__ __forceinline__ void ast64(void* p, u64 v){
  __hip_atomic_store((u64*)p, v, __ATOMIC_RELAXED, __HIP_MEMORY_SCOPE_AGENT);
}
__device__ __forceinline__ float aldf(const float* p){
  return __hip_atomic_load(p, __ATOMIC_RELAXED, __HIP_MEMORY_SCOPE_AGENT);
}
__device__ __forceinline__ void astf(float* p, float v){
  __hip_atomic_store(p, v, __ATOMIC_RELAXED, __HIP_MEMORY_SCOPE_AGENT);
}
__device__ __forceinline__ void ast32(u32* p, u32 v){
  __hip_atomic_store(p, v, __ATOMIC_RELAXED, __HIP_MEMORY_SCOPE_AGENT);
}
__device__ __forceinline__ bfrag8 aldfrag(const u16* p){
  union { u64 q[2]; bfrag8 f; } u;
  u.q[0] = ald64(p);
  u.q[1] = ald64(p + 4);
  return u.f;
}

// 16x16 tile MFMA loop, A-operand via LLC atomics, B-operand cached
__device__ __forceinline__ f32x4 mfma_loop_a(const u16* A, int lda,
                                             const u16* Bm, int ldb,
                                             int K, f32x4 acc){
  int lane = threadIdx.x & 63;
  const u16* pa = A + (size_t)(lane & 15) * lda + ((lane >> 4) * 8);
  const u16* pb = Bm + (size_t)(lane & 15) * ldb + ((lane >> 4) * 8);
  #pragma unroll 4
  for (int k = 0; k < K; k += 32){
    bfrag8 av = aldfrag(pa + k);
    bfrag8 bv = *(const bfrag8*)(pb + k);
    acc = __builtin_amdgcn_mfma_f32_16x16x32_bf16(av, bv, acc, 0, 0, 0);
  }
  return acc;
}
// fully-cached variant (for setup GEMMs)
__device__ __forceinline__ f32x4 mfma_loop(const u16* A, int lda,
                                           const u16* Bm, int ldb,
                                           int K, f32x4 acc){
  int lane = threadIdx.x & 63;
  const u16* pa = A + (size_t)(lane & 15) * lda + ((lane >> 4) * 8);
  const u16* pb = Bm + (size_t)(lane & 15) * ldb + ((lane >> 4) * 8);
  #pragma unroll 4
  for (int k = 0; k < K; k += 32){
    bfrag8 av = *(const bfrag8*)(pa + k);
    bfrag8 bv = *(const bfrag8*)(pb + k);
    acc = __builtin_amdgcn_mfma_f32_16x16x32_bf16(av, bv, acc, 0, 0, 0);
  }
  return acc;
}

// dataflow sync: cumulative counters, zero fences
__device__ __forceinline__ void waitc(int* c, int tgt){
  __syncthreads();
  if (threadIdx.x == 0){
    while (__hip_atomic_load(c, __ATOMIC_RELAXED, __HIP_MEMORY_SCOPE_AGENT) < tgt)
      __builtin_amdgcn_s_sleep(1);
  }
  __syncthreads();
}
__device__ __forceinline__ void signal(int* c){
  __syncthreads();   // drains this block's vmcnt -> data stores committed at LLC
  if (threadIdx.x == 0)
    __hip_atomic_fetch_add(c, 1, __ATOMIC_RELAXED, __HIP_MEMORY_SCOPE_AGENT);
}

// ---------------- setup kernels ----------------
__global__ __launch_bounds__(256) void k_zero(float* p, int n){
  int i = blockIdx.x*256 + threadIdx.x;
  if (i < n) p[i] = 0.f;
}
__global__ __launch_bounds__(256) void k_cvt(const float* src, u16* dst, int n){
  int i = blockIdx.x*256 + threadIdx.x, st = gridDim.x*256;
  for (; i < n; i += st) dst[i] = f2bf(src[i]);
}
// permuted-tile Wcat0: out[w][s][k]; row r=(s>>2)*1024+4w+(s&3); k<1024: Whh0, else Wih0 att cols
__global__ __launch_bounds__(256) void k_build_wc0p(const float* Whh0, const float* Wih0, u16* out){
  int i = blockIdx.x*256+threadIdx.x, n = 256*16*KX, st = gridDim.x*256;
  for (; i<n; i+=st){
    int k = i % KX, ws = i / KX;
    int s = ws & 15, w2 = ws >> 4;
    int r = (s>>2)*1024 + 4*w2 + (s&3);
    float v = (k < 1024) ? Whh0[(size_t)r*1024 + k] : Wih0[(size_t)r*KX + k];
    out[i] = f2bf(v);
  }
}
// permuted-tile Wcat1: k<1024: Wih1 (z0 half), else Whh1 (z1 half)
__global__ __launch_bounds__(256) void k_build_wc1p(const float* Wih1, const float* Whh1, u16* out){
  int i = blockIdx.x*256+threadIdx.x, n = 256*16*KA1, st = gridDim.x*256;
  for (; i<n; i+=st){
    int k = i % KA1, ws = i / KA1;
    int s = ws & 15, w2 = ws >> 4;
    int r = (s>>2)*1024 + 4*w2 + (s&3);
    float v = (k < 1024) ? Wih1[(size_t)r*1024 + k] : Whh1[(size_t)r*1024 + (k-1024)];
    out[i] = f2bf(v);
  }
}
__global__ __launch_bounds__(256) void k_build_wih0e(const float* Wih0, u16* out){
  int i = blockIdx.x*256+threadIdx.x, n = G4*DUNITS, st = gridDim.x*256;
  for (; i<n; i+=st){
    int j = i/DUNITS, k = i%DUNITS;
    out[i] = f2bf(Wih0[(size_t)j*KX + k]);
  }
}
__global__ __launch_bounds__(256) void k_build_aey(const float* embed, const int* ys_pad, u16* out){
  int i = blockIdx.x*256+threadIdx.x, n = NTOK*DUNITS, st = gridDim.x*256;
  for (; i<n; i+=st){
    int row = i / DUNITS, k = i % DUNITS;
    int l = row / Bsz, b = row % Bsz;
    int idx = (l == 0) ? SOS_ID : ys_pad[b*LMAX + (l-1)];
    out[i] = f2bf(embed[(size_t)idx*DUNITS + k]);
  }
}

__global__ __launch_bounds__(64) void k_gemm_preenc(const u16* hsb, const u16* Wenc,
                                                    const float* b_enc, u16* pre_enc){
  int bid = blockIdx.x;
  int m0 = (bid >> 5) * 16, n0 = (bid & 31) * 16;
  int lane = threadIdx.x & 63;
  int col = n0 + (lane & 15);
  float bias = b_enc[col];
  f32x4 acc = {bias, bias, bias, bias};
  acc = mfma_loop(hsb + (size_t)m0*EPROJS, EPROJS, Wenc + (size_t)n0*EPROJS, EPROJS, EPROJS, acc);
  int quad = lane >> 4;
  #pragma unroll
  for (int r = 0; r < 4; r++)
    pre_enc[(size_t)(m0 + quad*4 + r)*ATT + col] = f2bf(acc[r]);
}

__global__ __launch_bounds__(64) void k_gemm_pregate(const u16* Aey, const u16* Wih0e,
                                                     const float* b_ih0, const float* b_hh0, float* out){
  int bid = blockIdx.x;
  int m0 = (bid >> 8) * 16, n0 = (bid & 255) * 16;
  int lane = threadIdx.x & 63;
  int col = n0 + (lane & 15);
  float bias = b_ih0[col] + b_hh0[col];
  f32x4 acc = {bias, bias, bias, bias};
  acc = mfma_loop(Aey + (size_t)m0*DUNITS, DUNITS, Wih0e + (size_t)n0*DUNITS, DUNITS, DUNITS, acc);
  int quad = lane >> 4;
  #pragma unroll
  for (int r = 0; r < 4; r++)
    out[(size_t)(m0 + quad*4 + r)*G4 + col] = acc[r];
}

__global__ __launch_bounds__(64) void k_gemm_logits(const u16* zall, const u16* Woutb,
                                                    const float* b_out, float* logits){
  const int NT = 313;
  int bid = blockIdx.x;
  int m0 = (bid / NT) * 16, n0 = (bid % NT) * 16;
  int lane = threadIdx.x & 63;
  int col = n0 + (lane & 15);
  bool ok = col < ODIM;
  int brow = ok ? col : 0;
  float bias = ok ? b_out[col] : 0.f;
  f32x4 acc = {bias, bias, bias, bias};
  const u16* pa = zall + (size_t)m0*DUNITS + (size_t)(lane & 15)*DUNITS + (lane >> 4)*8;
  const u16* pb = Woutb + (size_t)brow*DUNITS + (lane >> 4)*8;
  #pragma unroll 4
  for (int k = 0; k < DUNITS; k += 32){
    bfrag8 av = *(const bfrag8*)(pa + k);
    bfrag8 bv = *(const bfrag8*)(pb + k);
    acc = __builtin_amdgcn_mfma_f32_16x16x32_bf16(av, bv, acc, 0, 0, 0);
  }
  int quad = lane >> 4;
  if (ok){
    #pragma unroll
    for (int r = 0; r < 4; r++)
      logits[(size_t)(m0 + quad*4 + r)*ODIM + col] = acc[r];
  }
}

__global__ __launch_bounds__(256) void k_nll(const float* logits, const int* ys_pad, float* nll){
  int n = blockIdx.x;
  int b = n & 15, l = n >> 4;
  const float* row = logits + (size_t)n * ODIM;
  __shared__ float red[256];
  float m = -1e30f;
  for (int i = threadIdx.x; i < ODIM; i += 256) m = fmaxf(m, row[i]);
  red[threadIdx.x] = m; __syncthreads();
  for (int s = 128; s > 0; s >>= 1){
    if (threadIdx.x < s) red[threadIdx.x] = fmaxf(red[threadIdx.x], red[threadIdx.x + s]);
    __syncthreads();
  }
  float M = red[0]; __syncthreads();
  float sum = 0.f;
  for (int i = threadIdx.x; i < ODIM; i += 256) sum += __expf(row[i] - M);
  red[threadIdx.x] = sum; __syncthreads();
  for (int s = 128; s > 0; s >>= 1){
    if (threadIdx.x < s) red[threadIdx.x] += red[threadIdx.x + s];
    __syncthreads();
  }
  if (threadIdx.x == 0){
    int tgt = (l < LMAX) ? ys_pad[b*LMAX + l] : (ODIM - 1);
    nll[n] = (M + __logf(red[0])) - row[tgt];
  }
}

__global__ __launch_bounds__(256) void k_loss(const float* nll, float* out){
  __shared__ float red[256];
  float s = 0.f;
  for (int i = threadIdx.x; i < NTOK; i += 256) s += nll[i];
  red[threadIdx.x] = s; __syncthreads();
  for (int st = 128; st > 0; st >>= 1){
    if (threadIdx.x < st) red[threadIdx.x] += red[threadIdx.x + st];
    __syncthreads();
  }
  if (threadIdx.x == 0) out[0] = red[0] * ((float)LMAX / (float)NTOK);
}

// ---------------- persistent recurrence kernel (dataflow-synced) ----------------
// counters in bar: c_z0=bar[0], c_z1=bar[32], c_dp=bar[64], c_att=bar[96],
// c_part[b]=bar[128+b*32]. All cumulative across the 97 steps.
__global__ __launch_bounds__(256, 2) void k_persist(
  const u16* __restrict__ peb, const u16* __restrict__ hsb,
  const u16* __restrict__ wc0p, const u16* __restrict__ wc1p, const u16* __restrict__ wdecb,
  const float* __restrict__ pg0, const float* __restrict__ b_ih1, const float* __restrict__ b_hh1,
  const float* __restrict__ gvec, const int* __restrict__ hlens,
  u16* a1b0, u16* a1b1, float* dpbuf, float* part, float* partS, u16* xatt,
  u16* zall, int* bar)
{
  __shared__ __align__(16) u16 s_pe[TCH*512];
  __shared__ __align__(16) u16 s_hs[TCH*512];
  __shared__ __align__(16) float s_dp[512];
  __shared__ __align__(16) float s_gv[512];
  __shared__ __align__(16) float s_red[2048];
  __shared__ float s_c[64];
  __shared__ float s_bias[16];
  __shared__ float s_sp[4];
  __shared__ __align__(8) u16 s_h[64];

  int tid = threadIdx.x, blk = blockIdx.x;
  int wv = tid >> 6, ln = tid & 63;
  int s2_b = blk >> 5, s2_ch = blk & 31;
  int t0 = s2_ch * TCH;
  int hl = hlens[s2_b];

  int* c_z0  = bar;
  int* c_z1  = bar + 32;
  int* c_dp  = bar + 64;
  int* c_att = bar + 96;
  int* c_part= bar + 128;

  // ---- init: stage LDS-persistent data ----
  {
    const bfrag8* src_pe = (const bfrag8*)(peb + ((size_t)(s2_b*Tlen + t0))*512);
    const bfrag8* src_hs = (const bfrag8*)(hsb + ((size_t)(s2_b*Tlen + t0))*512);
    for (int idx = tid; idx < TCH*512/8; idx += 256){
      ((bfrag8*)s_pe)[idx] = src_pe[idx];
      ((bfrag8*)s_hs)[idx] = src_hs[idx];
    }
    for (int a = tid; a < 512; a += 256) s_gv[a] = gvec[a];
    if (blk < 256 && tid < 16){
      int r = (tid>>2)*1024 + 4*blk + (tid&3);
      s_bias[tid] = b_ih1[r] + b_hh1[r];
    }
    if (tid < 64) s_c[tid] = 0.f;
  }
  __syncthreads();

  f32x4 acc0 = {0.f,0.f,0.f,0.f};

  for (int i = 0; i < OL; i++){
    int par = i & 1;
    const u16* a1r = par ? a1b1 : a1b0;
    u16* a1w = par ? a1b0 : a1b1;
    float* dpc   = dpbuf + (size_t)par*(16*512);
    float* partc = part  + (size_t)par*(16*32*512);
    float* pSc   = partS + (size_t)par*(16*32);
    u16*   xac   = xatt  + (size_t)par*(16*512);

    // ======== S1 ========
    if (blk < 256){
      if (i >= 1){
        waitc(c_z0, 256*i);
        if (i >= 2) waitc(c_z1, 256*(i-1));
        const u16* bt = wc1p + (size_t)blk*16*KA1;
        f32x4 acc = {0.f,0.f,0.f,0.f};
        acc = mfma_loop_a(a1r + wv*512, KA1, bt + wv*512, KA1, 512, acc);
        int q = ln >> 4;
        #pragma unroll
        for (int r = 0; r < 4; r++) s_red[wv*256 + (q*4+r)*16 + (ln & 15)] = acc[r];
        __syncthreads();
        {
          float val = s_red[tid] + s_red[256+tid] + s_red[512+tid] + s_red[768+tid]
                    + s_bias[tid & 15];
          s_red[1024 + tid] = val;
        }
        __syncthreads();
        if (tid < 64){
          int b = tid >> 2, jj = tid & 3;
          float gi = s_red[1024 + b*16 + jj];
          float gf = s_red[1024 + b*16 + 4 + jj];
          float gg = s_red[1024 + b*16 + 8 + jj];
          float go = s_red[1024 + b*16 + 12 + jj];
          float c = s_c[tid];
          float cn = sigm(gf)*c + sigm(gi)*tanh_f(gg);
          float h  = sigm(go)*tanh_f(cn);
          s_c[tid] = cn;
          s_h[tid] = f2bf(h);
        }
        __syncthreads();
        if (tid < 16){
          u64 hq = ((u64*)s_h)[tid];
          ast64(&a1w[tid*KA1 + 1024 + 4*blk], hq);
          *(u64*)&zall[((size_t)(i-1)*Bsz + tid)*DUNITS + 4*blk] = hq;
        }
        signal(c_z1);
      }
    } else {
      int w = blk - 256;
      if (i >= 1) waitc(c_z0, 256*i);
      const u16* bt0 = wc0p + (size_t)w*16*KX;
      acc0 = (f32x4){0.f,0.f,0.f,0.f};
      acc0 = mfma_loop_a(a1r + wv*256, KA1, bt0 + wv*256, KX, 256, acc0);
      if (w < 32){
        const u16* btd = wdecb + (size_t)w*16*DUNITS;
        f32x4 ad = {0.f,0.f,0.f,0.f};
        ad = mfma_loop_a(a1r + wv*256, KA1, btd + wv*256, DUNITS, 256, ad);
        int q = ln >> 4;
        #pragma unroll
        for (int r = 0; r < 4; r++) s_red[wv*256 + (q*4+r)*16 + (ln & 15)] = ad[r];
        __syncthreads();
        {
          float val = s_red[tid] + s_red[256+tid] + s_red[512+tid] + s_red[768+tid];
          int b = tid >> 4, al = tid & 15;
          astf(&dpc[b*512 + w*16 + al], val);
        }
        signal(c_dp);
      }
    }

    // ======== S2: energies + attc partials ========
    waitc(c_dp, 32*(i+1));
    ((u64*)s_dp)[tid] = ald64(((const u64*)(dpc + s2_b*512)) + tid);
    __syncthreads();
    {
      float dpr[8], gvr[8];
      {
        float4 d1 = *(const float4*)&s_dp[ln*8];
        float4 d2 = *(const float4*)&s_dp[ln*8+4];
        float4 g1 = *(const float4*)&s_gv[ln*8];
        float4 g2 = *(const float4*)&s_gv[ln*8+4];
        dpr[0]=d1.x; dpr[1]=d1.y; dpr[2]=d1.z; dpr[3]=d1.w;
        dpr[4]=d2.x; dpr[5]=d2.y; dpr[6]=d2.z; dpr[7]=d2.w;
        gvr[0]=g1.x; gvr[1]=g1.y; gvr[2]=g1.z; gvr[3]=g1.w;
        gvr[4]=g2.x; gvr[5]=g2.y; gvr[6]=g2.z; gvr[7]=g2.w;
      }
      float attc[8];
      #pragma unroll
      for (int j = 0; j < 8; j++) attc[j] = 0.f;
      float sp = 0.f;
      for (int lt = wv; lt < TCH; lt += 4){
        int t = t0 + lt;
        bool valid = (t < hl);
        float e = 0.f;
        if (valid){
          bfrag8 pv = *(const bfrag8*)&s_pe[lt*512 + ln*8];
          #pragma unroll
          for (int j = 0; j < 8; j++){
            float x = bf2f(((u16*)&pv)[j]) + dpr[j];
            e += gvr[j] * tanh_f(x);
          }
        }
        #pragma unroll
        for (int off = 32; off > 0; off >>= 1) e += __shfl_xor(e, off, 64);
        float p = valid ? __expf(2.0f * e) : 0.f;
        if (ln == 0) sp += p;
        bfrag8 hv = *(const bfrag8*)&s_hs[lt*512 + ln*8];
        #pragma unroll
        for (int j = 0; j < 8; j++) attc[j] += p * bf2f(((u16*)&hv)[j]);
      }
      *(float4*)&s_red[wv*512 + ln*8]     = make_float4(attc[0],attc[1],attc[2],attc[3]);
      *(float4*)&s_red[wv*512 + ln*8 + 4] = make_float4(attc[4],attc[5],attc[6],attc[7]);
      if (ln == 0) s_sp[wv] = sp;
      __syncthreads();
      {
        int e0 = 2*tid;
        float v0 = s_red[e0]   + s_red[512+e0]   + s_red[1024+e0]   + s_red[1536+e0];
        float v1 = s_red[e0+1] + s_red[512+e0+1] + s_red[1024+e0+1] + s_red[1536+e0+1];
        union { float f[2]; u64 q; } pu; pu.f[0]=v0; pu.f[1]=v1;
        ast64(&partc[((size_t)(s2_b*32 + s2_ch))*512 + e0], pu.q);
      }
      if (tid == 0) astf(&pSc[s2_b*32 + s2_ch], s_sp[0]+s_sp[1]+s_sp[2]+s_sp[3]);
      signal(&c_part[s2_b*32]);
    }

    // ======== S3: attc reduce + normalize (blocks 0..15) ========
    if (blk < 16){
      waitc(&c_part[blk*32], 32*(i+1));
      if (tid < 32) s_red[tid] = aldf(&pSc[blk*32 + tid]);
      __syncthreads();
      if (tid == 0){
        float s = 0.f;
        for (int c2 = 0; c2 < 32; c2++) s += s_red[c2];
        s_red[40] = 1.0f / s;
      }
      __syncthreads();
      float rinv = s_red[40];
      float v0 = 0.f, v1 = 0.f;
      int e0 = 2*tid;
      for (int c2 = 0; c2 < 32; c2++){
        union { u64 q; float f[2]; } pu;
        pu.q = ald64(&partc[((size_t)(blk*32 + c2))*512 + e0]);
        v0 += pu.f[0]; v1 += pu.f[1];
      }
      u32 w2 = (u32)f2bf(v0*rinv) | ((u32)f2bf(v1*rinv) << 16);
      ast32((u32*)&xac[blk*512 + e0], w2);
      signal(c_att);
    }

    // ======== S4: gates0 att-part + cell0 (blocks 256..511) ========
    if (blk >= 256){
      waitc(c_att, 16*(i+1));
      int w = blk - 256;
      const u16* bt0 = wc0p + (size_t)w*16*KX;
      acc0 = mfma_loop_a(xac + wv*128, 512, bt0 + 1024 + wv*128, KX, 128, acc0);
      int q = ln >> 4;
      #pragma unroll
      for (int r = 0; r < 4; r++) s_red[wv*256 + (q*4+r)*16 + (ln & 15)] = acc0[r];
      __syncthreads();
      {
        int b = tid >> 4, s = tid & 15;
        int r = (s>>2)*1024 + 4*w + (s&3);
        float val = s_red[tid] + s_red[256+tid] + s_red[512+tid] + s_red[768+tid]
                  + pg0[((size_t)(i*Bsz + b))*G4 + r];
        s_red[1024 + tid] = val;
      }
      __syncthreads();
      if (tid < 64){
        int b = tid >> 2, jj = tid & 3;
        float gi = s_red[1024 + b*16 + jj];
        float gf = s_red[1024 + b*16 + 4 + jj];
        float gg = s_red[1024 + b*16 + 8 + jj];
        float go = s_red[1024 + b*16 + 12 + jj];
        float c = s_c[tid];
        float cn = sigm(gf)*c + sigm(gi)*tanh_f(gg);
        float h  = sigm(go)*tanh_f(cn);
        s_c[tid] = cn;
        s_h[tid] = f2bf(h);
      }
      __syncthreads();
      if (tid < 16) ast64(&a1w[tid*KA1 + 4*w], ((u64*)s_h)[tid]);
      signal(c_z0);
    }
  }

  // ======== tail: gates1 + cell1 for step 96 ========
  if (blk < 256){
    waitc(c_z0, 256*OL);
    waitc(c_z1, 256*(OL-1));
    const u16* a1r = (OL & 1) ? a1b1 : a1b0;
    const u16* bt = wc1p + (size_t)blk*16*KA1;
    f32x4 acc = {0.f,0.f,0.f,0.f};
    acc = mfma_loop_a(a1r + wv*512, KA1, bt + wv*512, KA1, 512, acc);
    int q = ln >> 4;
    #pragma unroll
    for (int r = 0; r < 4; r++) s_red[wv*256 + (q*4+r)*16 + (ln & 15)] = acc[r];
    __syncthreads();
    {
      float val = s_red[tid] + s_red[256+tid] + s_red[512+tid] + s_red[768+tid]
                + s_bias[tid & 15];
      s_red[1024 + tid] = val;
    }
    __syncthreads();
    if (tid < 64){
      int b = tid >> 2, jj = tid & 3;
      float gi = s_red[1024 + b*16 + jj];
      float gf = s_red[1024 + b*16 + 4 + jj];
      float gg = s_red[1024 + b*16 + 8 + jj];
      float go = s_red[1024 + b*16 + 12 + jj];
      float c = s_c[tid];
      float cn = sigm(gf)*c + sigm(gi)*tanh_f(gg);
      float h  = sigm(go)*tanh_f(cn);
      s_h[tid] = f2bf(h);
    }
    __syncthreads();
    if (tid < 16)
      *(u64*)&zall[((size_t)LMAX*Bsz + tid)*DUNITS + 4*blk] = ((u64*)s_h)[tid];
  }
}

extern "C" void kernel_launch(void* const* d_in, const int* in_sizes, int n_in,
                              void* d_out, int out_size, void* d_ws, size_t ws_size,
                              hipStream_t stream)
{
  const float* hs     = (const float*)d_in[0];
  const int*   hlens  = (const int*)d_in[1];
  const int*   ys_pad = (const int*)d_in[2];
  const float* embed  = (const float*)d_in[3];
  const float* W_ih0  = (const float*)d_in[4];
  const float* W_hh0  = (const float*)d_in[5];
  const float* b_ih0  = (const float*)d_in[6];
  const float* b_hh0  = (const float*)d_in[7];
  const float* W_ih1  = (const float*)d_in[8];
  const float* W_hh1  = (const float*)d_in[9];
  const float* b_ih1  = (const float*)d_in[10];
  const float* b_hh1  = (const float*)d_in[11];
  const float* W_enc  = (const float*)d_in[12];
  const float* b_enc  = (const float*)d_in[13];
  const float* W_dec  = (const float*)d_in[14];
  const float* gvec   = (const float*)d_in[15];
  const float* W_out  = (const float*)d_in[16];
  const float* b_out  = (const float*)d_in[17];
  (void)in_sizes; (void)n_in; (void)out_size; (void)ws_size;

  char* w = (char*)d_ws;
  size_t off = 0;
  auto alloc = [&](size_t bytes)->char*{
    char* ptr = w + off;
    off += (bytes + 255) & ~(size_t)255;
    return ptr;
  };
  // --- zeroed state block: counters + a1 double buffers ---
  int*   bar  = (int*)alloc(4096);
  u16*  a1b0  = (u16*)alloc(Bsz*KA1*2);
  u16*  a1b1  = (u16*)alloc(Bsz*KA1*2);
  size_t state_bytes = off;
  // --- scratch (written before read every step) ---
  float* dpbuf = (float*)alloc(2*(size_t)Bsz*ATT*4);
  float* part  = (float*)alloc(2*(size_t)Bsz*32*512*4);
  float* partS = (float*)alloc(2*(size_t)Bsz*32*4);
  u16*  xatt   = (u16*)alloc(2*(size_t)Bsz*512*2);
  u16*  hsb    = (u16*)alloc((size_t)Bsz*Tlen*EPROJS*2);
  u16*  peb    = (u16*)alloc((size_t)Bsz*Tlen*ATT*2);
  u16*  wencb  = (u16*)alloc((size_t)ATT*EPROJS*2);
  u16*  wdecb  = (u16*)alloc((size_t)ATT*DUNITS*2);
  u16*  wc0p   = (u16*)alloc((size_t)G4*KX*2);
  u16*  wc1p   = (u16*)alloc((size_t)G4*KA1*2);
  u16*  woutb  = (u16*)alloc((size_t)ODIM*DUNITS*2);
  float* pg0   = (float*)alloc((size_t)NTOK*G4*4);
  u16*  zall   = (u16*)alloc((size_t)NTOK*DUNITS*2);
  float* logits= (float*)alloc((size_t)NTOK*ODIM*4);
  float* nll   = (float*)alloc(NTOK*4);
  // setup-only buffers aliased into logits region (dead once logits is written)
  u16*  wih0e  = (u16*)logits;
  u16*  aey    = (u16*)((char*)logits + (size_t)G4*DUNITS*2);

  {
    int n = (int)(state_bytes / 4);
    k_zero<<<(n + 255)/256, 256, 0, stream>>>((float*)w, n);
  }

  k_cvt<<<2048,256,0,stream>>>(hs, hsb, Bsz*Tlen*EPROJS);
  k_cvt<<<256,256,0,stream>>>(W_enc, wencb, ATT*EPROJS);
  k_cvt<<<512,256,0,stream>>>(W_dec, wdecb, ATT*DUNITS);
  k_cvt<<<2048,256,0,stream>>>(W_out, woutb, ODIM*DUNITS);
  k_build_wc0p<<<4096,256,0,stream>>>(W_hh0, W_ih0, wc0p);
  k_build_wc1p<<<4096,256,0,stream>>>(W_ih1, W_hh1, wc1p);
  k_build_wih0e<<<2048,256,0,stream>>>(W_ih0, wih0e);
  k_build_aey<<<1024,256,0,stream>>>(embed, ys_pad, aey);

  k_gemm_preenc<<<(Bsz*Tlen/16)*(ATT/16), 64, 0, stream>>>(hsb, wencb, b_enc, peb);
  k_gemm_pregate<<<OL*(G4/16), 64, 0, stream>>>(aey, wih0e, b_ih0, b_hh0, pg0);

  // persistent cooperative recurrence (dataflow-synced, no fences)
  {
    void* args[] = {
      (void*)&peb, (void*)&hsb, (void*)&wc0p, (void*)&wc1p, (void*)&wdecb,
      (void*)&pg0, (void*)&b_ih1, (void*)&b_hh1, (void*)&gvec, (void*)&hlens,
      (void*)&a1b0, (void*)&a1b1, (void*)&dpbuf, (void*)&part, (void*)&partS,
      (void*)&xatt, (void*)&zall, (void*)&bar
    };
    hipLaunchCooperativeKernel((const void*)k_persist, dim3(NWG), dim3(256),
                               args, 0, stream);
  }

  k_gemm_logits<<<OL*313, 64, 0, stream>>>(zall, woutb, b_out, logits);
  k_nll<<<NTOK,256,0,stream>>>(logits, ys_pad, nll);
  k_loss<<<1,256,0,stream>>>(nll, (float*)d_out);
}

// Round 6
// 4332.447 us; speedup vs baseline: 6.4481x; 1.2437x over previous
//
#include <hip/hip_runtime.h>
#include <stdint.h>

// Problem constants
#define Bsz 16
#define Tlen 800
#define EPROJS 512
#define DUNITS 1024
#define ATT 512
#define ODIM 5000
#define LMAX 96
#define OL 97
#define NTOK (OL*Bsz)
#define G4 (4*DUNITS)
#define KX 1536             // [z0(1024) ; att_c(512)]
#define KA1 2048            // [z0(1024) ; z1(1024)]
#define SOS_ID (ODIM-1)
#define NWG 512
#define TCH 25              // t per S2 chunk (32 chunks * 25 = 800)

typedef unsigned short u16;
typedef unsigned int u32;
typedef unsigned long long u64;
typedef short bfrag8 __attribute__((ext_vector_type(8)));
typedef float f32x4 __attribute__((ext_vector_type(4)));

__device__ __forceinline__ float bf2f(u16 u){
  union { uint32_t u; float f; } v; v.u = ((uint32_t)u) << 16; return v.f;
}
__device__ __forceinline__ u16 f2bf(float f){
  union { float f; uint32_t u; } v; v.f = f;
  uint32_t r = v.u + 0x7FFFu + ((v.u >> 16) & 1u);
  return (u16)(r >> 16);
}
__device__ __forceinline__ float sigm(float x){ return 1.0f/(1.0f + __expf(-x)); }
__device__ __forceinline__ float tanh_f(float x){ return 1.0f - 2.0f/(__expf(2.0f*x) + 1.0f); }

// ---- LLC-coherent (agent-scope relaxed atomic) access: bypasses L1/L2, no
// cache maintenance, no RMW serialization. All cross-block data uses these.
__device__ __forceinline__ u64 ald64(const void* p){
  return __hip_atomic_load((const u64*)p, __ATOMIC_RELAXED, __HIP_MEMORY_SCOPE_AGENT);
}
__device__ __forceinline__ void ast64(void* p, u64 v){
  __hip_atomic_store((u64*)p, v, __ATOMIC_RELAXED, __HIP_MEMORY_SCOPE_AGENT);
}
__device__ __forceinline__ float aldf(const float* p){
  return __hip_atomic_load(p, __ATOMIC_RELAXED, __HIP_MEMORY_SCOPE_AGENT);
}
__device__ __forceinline__ void astf(float* p, float v){
  __hip_atomic_store(p, v, __ATOMIC_RELAXED, __HIP_MEMORY_SCOPE_AGENT);
}
__device__ __forceinline__ void ast32(u32* p, u32 v){
  __hip_atomic_store(p, v, __ATOMIC_RELAXED, __HIP_MEMORY_SCOPE_AGENT);
}
__device__ __forceinline__ int ald32(const int* p){
  return __hip_atomic_load(p, __ATOMIC_RELAXED, __HIP_MEMORY_SCOPE_AGENT);
}
__device__ __forceinline__ bfrag8 aldfrag(const u16* p){
  union { u64 q[2]; bfrag8 f; } u;
  u.q[0] = ald64(p);
  u.q[1] = ald64(p + 4);
  return u.f;
}

// 16x16 tile MFMA loop, A-operand via LLC atomics, B-operand cached
__device__ __forceinline__ f32x4 mfma_loop_a(const u16* A, int lda,
                                             const u16* Bm, int ldb,
                                             int K, f32x4 acc){
  int lane = threadIdx.x & 63;
  const u16* pa = A + (size_t)(lane & 15) * lda + ((lane >> 4) * 8);
  const u16* pb = Bm + (size_t)(lane & 15) * ldb + ((lane >> 4) * 8);
  #pragma unroll 4
  for (int k = 0; k < K; k += 32){
    bfrag8 av = aldfrag(pa + k);
    bfrag8 bv = *(const bfrag8*)(pb + k);
    acc = __builtin_amdgcn_mfma_f32_16x16x32_bf16(av, bv, acc, 0, 0, 0);
  }
  return acc;
}
// fully-cached variant (setup GEMMs)
__device__ __forceinline__ f32x4 mfma_loop(const u16* A, int lda,
                                           const u16* Bm, int ldb,
                                           int K, f32x4 acc){
  int lane = threadIdx.x & 63;
  const u16* pa = A + (size_t)(lane & 15) * lda + ((lane >> 4) * 8);
  const u16* pb = Bm + (size_t)(lane & 15) * ldb + ((lane >> 4) * 8);
  #pragma unroll 4
  for (int k = 0; k < K; k += 32){
    bfrag8 av = *(const bfrag8*)(pa + k);
    bfrag8 bv = *(const bfrag8*)(pb + k);
    acc = __builtin_amdgcn_mfma_f32_16x16x32_bf16(av, bv, acc, 0, 0, 0);
  }
  return acc;
}

// ---- store-slot dataflow sync (no RMW, no fences) ----
// wave 0 polls n64 u64 words (= 2*n64 int epochs), all >= tgt.
__device__ __forceinline__ void wait_slots(const u64* s64, int n64, int tgt){
  __syncthreads();
  if (threadIdx.x < 64){
    int ln = threadIdx.x;
    for(;;){
      int mn = 0x7fffffff;
      for (int j = ln; j < n64; j += 64){
        u64 v = ald64(&s64[j]);
        int a = (int)(u32)v, b = (int)(u32)(v >> 32);
        mn = mn < a ? mn : a;
        mn = mn < b ? mn : b;
      }
      if (__all(mn >= tgt)) break;
      __builtin_amdgcn_s_sleep(4);
    }
  }
  __syncthreads();
}
// producer: data stores -> __syncthreads (vmcnt drained) -> own-slot store
__device__ __forceinline__ void signal_slot(int* slot, int val){
  __syncthreads();
  if (threadIdx.x == 0) ast32((u32*)slot, (u32)val);
}

// ---------------- setup kernels ----------------
__global__ __launch_bounds__(256) void k_zero(float* p, int n){
  int i = blockIdx.x*256 + threadIdx.x;
  if (i < n) p[i] = 0.f;
}
__global__ __launch_bounds__(256) void k_cvt(const float* src, u16* dst, int n){
  int i = blockIdx.x*256 + threadIdx.x, st = gridDim.x*256;
  for (; i < n; i += st) dst[i] = f2bf(src[i]);
}
// permuted-tile Wcat0: out[w][s][k]; row r=(s>>2)*1024+4w+(s&3); k<1024: Whh0, else Wih0 att cols
__global__ __launch_bounds__(256) void k_build_wc0p(const float* Whh0, const float* Wih0, u16* out){
  int i = blockIdx.x*256+threadIdx.x, n = 256*16*KX, st = gridDim.x*256;
  for (; i<n; i+=st){
    int k = i % KX, ws = i / KX;
    int s = ws & 15, w2 = ws >> 4;
    int r = (s>>2)*1024 + 4*w2 + (s&3);
    float v = (k < 1024) ? Whh0[(size_t)r*1024 + k] : Wih0[(size_t)r*KX + k];
    out[i] = f2bf(v);
  }
}
// permuted-tile Wcat1: k<1024: Wih1 (z0 half), else Whh1 (z1 half)
__global__ __launch_bounds__(256) void k_build_wc1p(const float* Wih1, const float* Whh1, u16* out){
  int i = blockIdx.x*256+threadIdx.x, n = 256*16*KA1, st = gridDim.x*256;
  for (; i<n; i+=st){
    int k = i % KA1, ws = i / KA1;
    int s = ws & 15, w2 = ws >> 4;
    int r = (s>>2)*1024 + 4*w2 + (s&3);
    float v = (k < 1024) ? Wih1[(size_t)r*1024 + k] : Whh1[(size_t)r*1024 + (k-1024)];
    out[i] = f2bf(v);
  }
}
__global__ __launch_bounds__(256) void k_build_wih0e(const float* Wih0, u16* out){
  int i = blockIdx.x*256+threadIdx.x, n = G4*DUNITS, st = gridDim.x*256;
  for (; i<n; i+=st){
    int j = i/DUNITS, k = i%DUNITS;
    out[i] = f2bf(Wih0[(size_t)j*KX + k]);
  }
}
__global__ __launch_bounds__(256) void k_build_aey(const float* embed, const int* ys_pad, u16* out){
  int i = blockIdx.x*256+threadIdx.x, n = NTOK*DUNITS, st = gridDim.x*256;
  for (; i<n; i+=st){
    int row = i / DUNITS, k = i % DUNITS;
    int l = row / Bsz, b = row % Bsz;
    int idx = (l == 0) ? SOS_ID : ys_pad[b*LMAX + (l-1)];
    out[i] = f2bf(embed[(size_t)idx*DUNITS + k]);
  }
}

__global__ __launch_bounds__(64) void k_gemm_preenc(const u16* hsb, const u16* Wenc,
                                                    const float* b_enc, u16* pre_enc){
  int bid = blockIdx.x;
  int m0 = (bid >> 5) * 16, n0 = (bid & 31) * 16;
  int lane = threadIdx.x & 63;
  int col = n0 + (lane & 15);
  float bias = b_enc[col];
  f32x4 acc = {bias, bias, bias, bias};
  acc = mfma_loop(hsb + (size_t)m0*EPROJS, EPROJS, Wenc + (size_t)n0*EPROJS, EPROJS, EPROJS, acc);
  int quad = lane >> 4;
  #pragma unroll
  for (int r = 0; r < 4; r++)
    pre_enc[(size_t)(m0 + quad*4 + r)*ATT + col] = f2bf(acc[r]);
}

__global__ __launch_bounds__(64) void k_gemm_pregate(const u16* Aey, const u16* Wih0e,
                                                     const float* b_ih0, const float* b_hh0, float* out){
  int bid = blockIdx.x;
  int m0 = (bid >> 8) * 16, n0 = (bid & 255) * 16;
  int lane = threadIdx.x & 63;
  int col = n0 + (lane & 15);
  float bias = b_ih0[col] + b_hh0[col];
  f32x4 acc = {bias, bias, bias, bias};
  acc = mfma_loop(Aey + (size_t)m0*DUNITS, DUNITS, Wih0e + (size_t)n0*DUNITS, DUNITS, DUNITS, acc);
  int quad = lane >> 4;
  #pragma unroll
  for (int r = 0; r < 4; r++)
    out[(size_t)(m0 + quad*4 + r)*G4 + col] = acc[r];
}

__global__ __launch_bounds__(64) void k_gemm_logits(const u16* zall, const u16* Woutb,
                                                    const float* b_out, float* logits){
  const int NT = 313;
  int bid = blockIdx.x;
  int m0 = (bid / NT) * 16, n0 = (bid % NT) * 16;
  int lane = threadIdx.x & 63;
  int col = n0 + (lane & 15);
  bool ok = col < ODIM;
  int brow = ok ? col : 0;
  float bias = ok ? b_out[col] : 0.f;
  f32x4 acc = {bias, bias, bias, bias};
  const u16* pa = zall + (size_t)m0*DUNITS + (size_t)(lane & 15)*DUNITS + (lane >> 4)*8;
  const u16* pb = Woutb + (size_t)brow*DUNITS + (lane >> 4)*8;
  #pragma unroll 4
  for (int k = 0; k < DUNITS; k += 32){
    bfrag8 av = *(const bfrag8*)(pa + k);
    bfrag8 bv = *(const bfrag8*)(pb + k);
    acc = __builtin_amdgcn_mfma_f32_16x16x32_bf16(av, bv, acc, 0, 0, 0);
  }
  int quad = lane >> 4;
  if (ok){
    #pragma unroll
    for (int r = 0; r < 4; r++)
      logits[(size_t)(m0 + quad*4 + r)*ODIM + col] = acc[r];
  }
}

__global__ __launch_bounds__(256) void k_nll(const float* logits, const int* ys_pad, float* nll){
  int n = blockIdx.x;
  int b = n & 15, l = n >> 4;
  const float* row = logits + (size_t)n * ODIM;
  __shared__ float red[256];
  float m = -1e30f;
  for (int i = threadIdx.x; i < ODIM; i += 256) m = fmaxf(m, row[i]);
  red[threadIdx.x] = m; __syncthreads();
  for (int s = 128; s > 0; s >>= 1){
    if (threadIdx.x < s) red[threadIdx.x] = fmaxf(red[threadIdx.x], red[threadIdx.x + s]);
    __syncthreads();
  }
  float M = red[0]; __syncthreads();
  float sum = 0.f;
  for (int i = threadIdx.x; i < ODIM; i += 256) sum += __expf(row[i] - M);
  red[threadIdx.x] = sum; __syncthreads();
  for (int s = 128; s > 0; s >>= 1){
    if (threadIdx.x < s) red[threadIdx.x] += red[threadIdx.x + s];
    __syncthreads();
  }
  if (threadIdx.x == 0){
    int tgt = (l < LMAX) ? ys_pad[b*LMAX + l] : (ODIM - 1);
    nll[n] = (M + __logf(red[0])) - row[tgt];
  }
}

__global__ __launch_bounds__(256) void k_loss(const float* nll, float* out){
  __shared__ float red[256];
  float s = 0.f;
  for (int i = threadIdx.x; i < NTOK; i += 256) s += nll[i];
  red[threadIdx.x] = s; __syncthreads();
  for (int st = 128; st > 0; st >>= 1){
    if (threadIdx.x < st) red[threadIdx.x] += red[threadIdx.x + st];
    __syncthreads();
  }
  if (threadIdx.x == 0) out[0] = red[0] * ((float)LMAX / (float)NTOK);
}

// ---------------- persistent recurrence kernel (store-slot dataflow) ----------------
// slot layout (ints) in bar:
//   z0s[256] @0    : S4 block w2 stores i+1 at iter i
//   z1s[256] @256  : role-A blk stores i+1 at iter i (i>=1)
//   dps[32]  @512  : dp block w stores i+1 at iter i
//   atts[16] @544  : S3 block b stores i+1 at iter i
//   parts[16][32] @576 : S2 block stores i+1 at iter i
__global__ __launch_bounds__(256, 2) void k_persist(
  const u16* __restrict__ peb, const u16* __restrict__ hsb,
  const u16* __restrict__ wc0p, const u16* __restrict__ wc1p, const u16* __restrict__ wdecb,
  const float* __restrict__ pg0, const float* __restrict__ b_ih1, const float* __restrict__ b_hh1,
  const float* __restrict__ gvec, const int* __restrict__ hlens,
  u16* a1b0, u16* a1b1, float* dpbuf, float* part, float* partS, u16* xatt,
  u16* zall, int* bar)
{
  __shared__ __align__(16) u16 s_pe[TCH*512];
  __shared__ __align__(16) u16 s_hs[TCH*512];
  __shared__ __align__(16) float s_dp[512];
  __shared__ __align__(16) float s_gv[512];
  __shared__ __align__(16) float s_red[2048];
  __shared__ float s_c[64];
  __shared__ float s_bias[16];
  __shared__ float s_sp[4];
  __shared__ __align__(8) u16 s_h[64];

  int tid = threadIdx.x, blk = blockIdx.x;
  int wv = tid >> 6, ln = tid & 63;
  int s2_b = blk >> 5, s2_ch = blk & 31;
  int t0 = s2_ch * TCH;
  int hl = hlens[s2_b];

  int* z0s  = bar;
  int* z1s  = bar + 256;
  int* dps  = bar + 512;
  int* atts = bar + 544;
  int* parts= bar + 576;

  // ---- init: stage LDS-persistent data ----
  {
    const bfrag8* src_pe = (const bfrag8*)(peb + ((size_t)(s2_b*Tlen + t0))*512);
    const bfrag8* src_hs = (const bfrag8*)(hsb + ((size_t)(s2_b*Tlen + t0))*512);
    for (int idx = tid; idx < TCH*512/8; idx += 256){
      ((bfrag8*)s_pe)[idx] = src_pe[idx];
      ((bfrag8*)s_hs)[idx] = src_hs[idx];
    }
    for (int a = tid; a < 512; a += 256) s_gv[a] = gvec[a];
    if (blk < 256 && tid < 16){
      int r = (tid>>2)*1024 + 4*blk + (tid&3);
      s_bias[tid] = b_ih1[r] + b_hh1[r];
    }
    if (tid < 64) s_c[tid] = 0.f;
  }
  __syncthreads();

  f32x4 acc0 = {0.f,0.f,0.f,0.f};

  for (int i = 0; i < OL; i++){
    int par = i & 1;
    const u16* a1r = par ? a1b1 : a1b0;
    u16* a1w = par ? a1b0 : a1b1;
    float* dpc   = dpbuf + (size_t)par*(16*512);
    float* partc = part  + (size_t)par*(16*32*512);
    float* pSc   = partS + (size_t)par*(16*32);
    u16*   xac   = xatt  + (size_t)par*(16*512);

    // ======== S1 ========
    if (blk < 256){
      if (i >= 1){
        wait_slots((const u64*)z0s, 128, i);
        if (i >= 2) wait_slots((const u64*)z1s, 128, i);
        const u16* bt = wc1p + (size_t)blk*16*KA1;
        f32x4 acc = {0.f,0.f,0.f,0.f};
        acc = mfma_loop_a(a1r + wv*512, KA1, bt + wv*512, KA1, 512, acc);
        int q = ln >> 4;
        #pragma unroll
        for (int r = 0; r < 4; r++) s_red[wv*256 + (q*4+r)*16 + (ln & 15)] = acc[r];
        __syncthreads();
        {
          float val = s_red[tid] + s_red[256+tid] + s_red[512+tid] + s_red[768+tid]
                    + s_bias[tid & 15];
          s_red[1024 + tid] = val;
        }
        __syncthreads();
        if (tid < 64){
          int b = tid >> 2, jj = tid & 3;
          float gi = s_red[1024 + b*16 + jj];
          float gf = s_red[1024 + b*16 + 4 + jj];
          float gg = s_red[1024 + b*16 + 8 + jj];
          float go = s_red[1024 + b*16 + 12 + jj];
          float c = s_c[tid];
          float cn = sigm(gf)*c + sigm(gi)*tanh_f(gg);
          float h  = sigm(go)*tanh_f(cn);
          s_c[tid] = cn;
          s_h[tid] = f2bf(h);
        }
        __syncthreads();
        if (tid < 16){
          u64 hq = ((u64*)s_h)[tid];
          ast64(&a1w[tid*KA1 + 1024 + 4*blk], hq);
          *(u64*)&zall[((size_t)(i-1)*Bsz + tid)*DUNITS + 4*blk] = hq;
        }
        signal_slot(&z1s[blk], i + 1);
      }
    } else {
      int w = blk - 256;
      if (i >= 1) wait_slots((const u64*)z0s, 128, i);
      const u16* bt0 = wc0p + (size_t)w*16*KX;
      acc0 = (f32x4){0.f,0.f,0.f,0.f};
      acc0 = mfma_loop_a(a1r + wv*256, KA1, bt0 + wv*256, KX, 256, acc0);
      if (w < 32){
        const u16* btd = wdecb + (size_t)w*16*DUNITS;
        f32x4 ad = {0.f,0.f,0.f,0.f};
        ad = mfma_loop_a(a1r + wv*256, KA1, btd + wv*256, DUNITS, 256, ad);
        int q = ln >> 4;
        #pragma unroll
        for (int r = 0; r < 4; r++) s_red[wv*256 + (q*4+r)*16 + (ln & 15)] = ad[r];
        __syncthreads();
        {
          float val = s_red[tid] + s_red[256+tid] + s_red[512+tid] + s_red[768+tid];
          int b = tid >> 4, al = tid & 15;
          astf(&dpc[b*512 + w*16 + al], val);
        }
        signal_slot(&dps[w], i + 1);
      }
    }

    // ======== S2: energies + attc partials ========
    wait_slots((const u64*)dps, 16, i + 1);
    ((u64*)s_dp)[tid] = ald64(((const u64*)(dpc + s2_b*512)) + tid);
    __syncthreads();
    {
      float dpr[8], gvr[8];
      {
        float4 d1 = *(const float4*)&s_dp[ln*8];
        float4 d2 = *(const float4*)&s_dp[ln*8+4];
        float4 g1 = *(const float4*)&s_gv[ln*8];
        float4 g2 = *(const float4*)&s_gv[ln*8+4];
        dpr[0]=d1.x; dpr[1]=d1.y; dpr[2]=d1.z; dpr[3]=d1.w;
        dpr[4]=d2.x; dpr[5]=d2.y; dpr[6]=d2.z; dpr[7]=d2.w;
        gvr[0]=g1.x; gvr[1]=g1.y; gvr[2]=g1.z; gvr[3]=g1.w;
        gvr[4]=g2.x; gvr[5]=g2.y; gvr[6]=g2.z; gvr[7]=g2.w;
      }
      float attc[8];
      #pragma unroll
      for (int j = 0; j < 8; j++) attc[j] = 0.f;
      float sp = 0.f;
      for (int lt = wv; lt < TCH; lt += 4){
        int t = t0 + lt;
        bool valid = (t < hl);
        float e = 0.f;
        if (valid){
          bfrag8 pv = *(const bfrag8*)&s_pe[lt*512 + ln*8];
          #pragma unroll
          for (int j = 0; j < 8; j++){
            float x = bf2f(((u16*)&pv)[j]) + dpr[j];
            e += gvr[j] * tanh_f(x);
          }
        }
        #pragma unroll
        for (int off = 32; off > 0; off >>= 1) e += __shfl_xor(e, off, 64);
        float p = valid ? __expf(2.0f * e) : 0.f;
        if (ln == 0) sp += p;
        bfrag8 hv = *(const bfrag8*)&s_hs[lt*512 + ln*8];
        #pragma unroll
        for (int j = 0; j < 8; j++) attc[j] += p * bf2f(((u16*)&hv)[j]);
      }
      *(float4*)&s_red[wv*512 + ln*8]     = make_float4(attc[0],attc[1],attc[2],attc[3]);
      *(float4*)&s_red[wv*512 + ln*8 + 4] = make_float4(attc[4],attc[5],attc[6],attc[7]);
      if (ln == 0) s_sp[wv] = sp;
      __syncthreads();
      {
        int e0 = 2*tid;
        float v0 = s_red[e0]   + s_red[512+e0]   + s_red[1024+e0]   + s_red[1536+e0];
        float v1 = s_red[e0+1] + s_red[512+e0+1] + s_red[1024+e0+1] + s_red[1536+e0+1];
        union { float f[2]; u64 q; } pu; pu.f[0]=v0; pu.f[1]=v1;
        ast64(&partc[((size_t)(s2_b*32 + s2_ch))*512 + e0], pu.q);
      }
      if (tid == 0) astf(&pSc[s2_b*32 + s2_ch], s_sp[0]+s_sp[1]+s_sp[2]+s_sp[3]);
      signal_slot(&parts[s2_b*32 + s2_ch], i + 1);
    }

    // ======== S3: attc reduce + normalize (blocks 0..15) ========
    if (blk < 16){
      wait_slots((const u64*)(parts + blk*32), 16, i + 1);
      if (tid < 32) s_red[tid] = aldf(&pSc[blk*32 + tid]);
      __syncthreads();
      if (tid == 0){
        float s = 0.f;
        for (int c2 = 0; c2 < 32; c2++) s += s_red[c2];
        s_red[40] = 1.0f / s;
      }
      __syncthreads();
      float rinv = s_red[40];
      float v0 = 0.f, v1 = 0.f;
      int e0 = 2*tid;
      for (int c2 = 0; c2 < 32; c2++){
        union { u64 q; float f[2]; } pu;
        pu.q = ald64(&partc[((size_t)(blk*32 + c2))*512 + e0]);
        v0 += pu.f[0]; v1 += pu.f[1];
      }
      u32 w2 = (u32)f2bf(v0*rinv) | ((u32)f2bf(v1*rinv) << 16);
      ast32((u32*)&xac[blk*512 + e0], w2);
      signal_slot(&atts[blk], i + 1);
    }

    // ======== S4: gates0 att-part + cell0 (blocks 256..511) ========
    if (blk >= 256){
      wait_slots((const u64*)atts, 8, i + 1);
      int w = blk - 256;
      const u16* bt0 = wc0p + (size_t)w*16*KX;
      acc0 = mfma_loop_a(xac + wv*128, 512, bt0 + 1024 + wv*128, KX, 128, acc0);
      int q = ln >> 4;
      #pragma unroll
      for (int r = 0; r < 4; r++) s_red[wv*256 + (q*4+r)*16 + (ln & 15)] = acc0[r];
      __syncthreads();
      {
        int b = tid >> 4, s = tid & 15;
        int r = (s>>2)*1024 + 4*w + (s&3);
        float val = s_red[tid] + s_red[256+tid] + s_red[512+tid] + s_red[768+tid]
                  + pg0[((size_t)(i*Bsz + b))*G4 + r];
        s_red[1024 + tid] = val;
      }
      __syncthreads();
      if (tid < 64){
        int b = tid >> 2, jj = tid & 3;
        float gi = s_red[1024 + b*16 + jj];
        float gf = s_red[1024 + b*16 + 4 + jj];
        float gg = s_red[1024 + b*16 + 8 + jj];
        float go = s_red[1024 + b*16 + 12 + jj];
        float c = s_c[tid];
        float cn = sigm(gf)*c + sigm(gi)*tanh_f(gg);
        float h  = sigm(go)*tanh_f(cn);
        s_c[tid] = cn;
        s_h[tid] = f2bf(h);
      }
      __syncthreads();
      if (tid < 16) ast64(&a1w[tid*KA1 + 4*w], ((u64*)s_h)[tid]);
      signal_slot(&z0s[w], i + 1);
    }
  }

  // ======== tail: gates1 + cell1 for step 96 ========
  if (blk < 256){
    wait_slots((const u64*)z0s, 128, OL);
    wait_slots((const u64*)z1s, 128, OL);
    const u16* a1r = (OL & 1) ? a1b1 : a1b0;
    const u16* bt = wc1p + (size_t)blk*16*KA1;
    f32x4 acc = {0.f,0.f,0.f,0.f};
    acc = mfma_loop_a(a1r + wv*512, KA1, bt + wv*512, KA1, 512, acc);
    int q = ln >> 4;
    #pragma unroll
    for (int r = 0; r < 4; r++) s_red[wv*256 + (q*4+r)*16 + (ln & 15)] = acc[r];
    __syncthreads();
    {
      float val = s_red[tid] + s_red[256+tid] + s_red[512+tid] + s_red[768+tid]
                + s_bias[tid & 15];
      s_red[1024 + tid] = val;
    }
    __syncthreads();
    if (tid < 64){
      int b = tid >> 2, jj = tid & 3;
      float gi = s_red[1024 + b*16 + jj];
      float gf = s_red[1024 + b*16 + 4 + jj];
      float gg = s_red[1024 + b*16 + 8 + jj];
      float go = s_red[1024 + b*16 + 12 + jj];
      float c = s_c[tid];
      float cn = sigm(gf)*c + sigm(gi)*tanh_f(gg);
      float h  = sigm(go)*tanh_f(cn);
      s_h[tid] = f2bf(h);
    }
    __syncthreads();
    if (tid < 16)
      *(u64*)&zall[((size_t)LMAX*Bsz + tid)*DUNITS + 4*blk] = ((u64*)s_h)[tid];
  }
}

extern "C" void kernel_launch(void* const* d_in, const int* in_sizes, int n_in,
                              void* d_out, int out_size, void* d_ws, size_t ws_size,
                              hipStream_t stream)
{
  const float* hs     = (const float*)d_in[0];
  const int*   hlens  = (const int*)d_in[1];
  const int*   ys_pad = (const int*)d_in[2];
  const float* embed  = (const float*)d_in[3];
  const float* W_ih0  = (const float*)d_in[4];
  const float* W_hh0  = (const float*)d_in[5];
  const float* b_ih0  = (const float*)d_in[6];
  const float* b_hh0  = (const float*)d_in[7];
  const float* W_ih1  = (const float*)d_in[8];
  const float* W_hh1  = (const float*)d_in[9];
  const float* b_ih1  = (const float*)d_in[10];
  const float* b_hh1  = (const float*)d_in[11];
  const float* W_enc  = (const float*)d_in[12];
  const float* b_enc  = (const float*)d_in[13];
  const float* W_dec  = (const float*)d_in[14];
  const float* gvec   = (const float*)d_in[15];
  const float* W_out  = (const float*)d_in[16];
  const float* b_out  = (const float*)d_in[17];
  (void)in_sizes; (void)n_in; (void)out_size; (void)ws_size;

  char* w = (char*)d_ws;
  size_t off = 0;
  auto alloc = [&](size_t bytes)->char*{
    char* ptr = w + off;
    off += (bytes + 255) & ~(size_t)255;
    return ptr;
  };
  // --- zeroed state block: slots + a1 double buffers ---
  int*   bar  = (int*)alloc(8192);
  u16*  a1b0  = (u16*)alloc(Bsz*KA1*2);
  u16*  a1b1  = (u16*)alloc(Bsz*KA1*2);
  size_t state_bytes = off;
  // --- scratch (written before read every step) ---
  float* dpbuf = (float*)alloc(2*(size_t)Bsz*ATT*4);
  float* part  = (float*)alloc(2*(size_t)Bsz*32*512*4);
  float* partS = (float*)alloc(2*(size_t)Bsz*32*4);
  u16*  xatt   = (u16*)alloc(2*(size_t)Bsz*512*2);
  u16*  hsb    = (u16*)alloc((size_t)Bsz*Tlen*EPROJS*2);
  u16*  peb    = (u16*)alloc((size_t)Bsz*Tlen*ATT*2);
  u16*  wencb  = (u16*)alloc((size_t)ATT*EPROJS*2);
  u16*  wdecb  = (u16*)alloc((size_t)ATT*DUNITS*2);
  u16*  wc0p   = (u16*)alloc((size_t)G4*KX*2);
  u16*  wc1p   = (u16*)alloc((size_t)G4*KA1*2);
  u16*  woutb  = (u16*)alloc((size_t)ODIM*DUNITS*2);
  float* pg0   = (float*)alloc((size_t)NTOK*G4*4);
  u16*  zall   = (u16*)alloc((size_t)NTOK*DUNITS*2);
  float* logits= (float*)alloc((size_t)NTOK*ODIM*4);
  float* nll   = (float*)alloc(NTOK*4);
  // setup-only buffers aliased into logits region (dead once logits is written)
  u16*  wih0e  = (u16*)logits;
  u16*  aey    = (u16*)((char*)logits + (size_t)G4*DUNITS*2);

  {
    int n = (int)(state_bytes / 4);
    k_zero<<<(n + 255)/256, 256, 0, stream>>>((float*)w, n);
  }

  k_cvt<<<2048,256,0,stream>>>(hs, hsb, Bsz*Tlen*EPROJS);
  k_cvt<<<256,256,0,stream>>>(W_enc, wencb, ATT*EPROJS);
  k_cvt<<<512,256,0,stream>>>(W_dec, wdecb, ATT*DUNITS);
  k_cvt<<<2048,256,0,stream>>>(W_out, woutb, ODIM*DUNITS);
  k_build_wc0p<<<4096,256,0,stream>>>(W_hh0, W_ih0, wc0p);
  k_build_wc1p<<<4096,256,0,stream>>>(W_ih1, W_hh1, wc1p);
  k_build_wih0e<<<2048,256,0,stream>>>(W_ih0, wih0e);
  k_build_aey<<<1024,256,0,stream>>>(embed, ys_pad, aey);

  k_gemm_preenc<<<(Bsz*Tlen/16)*(ATT/16), 64, 0, stream>>>(hsb, wencb, b_enc, peb);
  k_gemm_pregate<<<OL*(G4/16), 64, 0, stream>>>(aey, wih0e, b_ih0, b_hh0, pg0);

  // persistent cooperative recurrence (store-slot dataflow, no RMW, no fences)
  {
    void* args[] = {
      (void*)&peb, (void*)&hsb, (void*)&wc0p, (void*)&wc1p, (void*)&wdecb,
      (void*)&pg0, (void*)&b_ih1, (void*)&b_hh1, (void*)&gvec, (void*)&hlens,
      (void*)&a1b0, (void*)&a1b1, (void*)&dpbuf, (void*)&part, (void*)&partS,
      (void*)&xatt, (void*)&zall, (void*)&bar
    };
    hipLaunchCooperativeKernel((const void*)k_persist, dim3(NWG), dim3(256),
                               args, 0, stream);
  }

  k_gemm_logits<<<OL*313, 64, 0, stream>>>(zall, woutb, b_out, logits);
  k_nll<<<NTOK,256,0,stream>>>(logits, ys_pad, nll);
  k_loss<<<1,256,0,stream>>>(nll, (float*)d_out);
}